// Round 11
// baseline (724.964 us; speedup 1.0000x reference)
//
#include <hip/hip_runtime.h>

// Transformer_67748814127473 — round 10: attn = R8 dual-sub-slice core (verified)
// + LDS-staged shared K/V tile stream (global_load_lds dbuf) + full VGPR budget
// via 128-thread/(128,1) blocks. B=8, T=1024, N=2048, E=256, L=4.

#define BB 8
#define TT 1024
#define NN 2048
#define EE 256
#define LL 4

typedef __attribute__((ext_vector_type(8))) short short8;
typedef __attribute__((ext_vector_type(4))) float f32x4;

__device__ inline ushort f2b(float f) {
    union { float f; unsigned u; } x; x.f = f;
    unsigned u = x.u;
    return (ushort)((u + 0x7fffu + ((u >> 16) & 1u)) >> 16);
}
__device__ inline unsigned cvtpk(float lo, float hi) {
    unsigned r;
    asm volatile("v_cvt_pk_bf16_f32 %0, %1, %2" : "=v"(r) : "v"(lo), "v"(hi));
    return r;
}
// fragment-linear pack for K=256 operands: tile16(row) x kchunk32 -> [lane][8]
__device__ inline size_t pk256(int row, int k) {
    return ((size_t)((row >> 4) * 8 + (k >> 5))) * 512
         + (size_t)((((k >> 3) & 3) * 16 + (row & 15)) * 8 + (k & 7));
}
// V pack: (batch, token n, embed e) -> B-frag linear
__device__ inline size_t vpk_idx(int bb, int nn, int e) {
    return ((size_t)(bb*64 + (nn >> 5)) * 16 + (e >> 4)) * 512
         + (size_t)((((nn >> 3) & 3) * 16 + (e & 15)) * 8 + (nn & 7));
}

// ---------------- weight prep: transpose + cast + frag-pack ----------------
__global__ __launch_bounds__(256) void wprep_k(
    const float* __restrict__ Wq, const float* __restrict__ Wk,
    const float* __restrict__ Wv, const float* __restrict__ W1,
    const float* __restrict__ W2,
    ushort* __restrict__ WQKt, ushort* __restrict__ WVt,
    ushort* __restrict__ W1t, ushort* __restrict__ W2t)
{
    int id = blockIdx.x;          // 320 = 20 matrices x 16 tiles
    int m = id >> 4, t = id & 15;
    int l = m / 5, which = m % 5;
    const float* src; ushort* dst;
    size_t o = (size_t)l * 65536;
    switch (which) {
        case 0: src = Wq + o; dst = WQKt + (size_t)l*131072;          break;
        case 1: src = Wk + o; dst = WQKt + (size_t)l*131072 + 65536;  break;
        case 2: src = Wv + o; dst = WVt + o; break;
        case 3: src = W1 + o; dst = W1t + o; break;
        default: src = W2 + o; dst = W2t + o; break;
    }
    int tk = (t >> 2) * 64;   // k block
    int tn = (t & 3) * 64;    // n block (output col)
    __shared__ ushort T[64][68];
    int tid = threadIdx.x;
    int r = tid >> 4, c4 = (tid & 15) * 4;
    #pragma unroll
    for (int it = 0; it < 4; ++it) {
        int k = r + it*16;
        float4 v = *(const float4*)&src[(size_t)(tk + k)*256 + tn + c4];
        T[k][c4+0] = f2b(v.x); T[k][c4+1] = f2b(v.y);
        T[k][c4+2] = f2b(v.z); T[k][c4+3] = f2b(v.w);
    }
    __syncthreads();
    #pragma unroll
    for (int it = 0; it < 4; ++it) {
        int n = tn + r + it*16;
        int k0 = tk + c4;
        ushort4 ov;
        ov.x = T[c4+0][n-tn]; ov.y = T[c4+1][n-tn];
        ov.z = T[c4+2][n-tn]; ov.w = T[c4+3][n-tn];
        *(ushort4*)&dst[pk256(n, k0)] = ov;
    }
}

// ---------------- per-batch even-row base vector ----------------
__global__ __launch_bounds__(256) void base_even_k(
    const float* __restrict__ aset, const float* __restrict__ We,
    const float* __restrict__ be, float* __restrict__ BE)
{
    int b = blockIdx.x; int e = threadIdx.x;
    __shared__ float as[640];
    for (int i = e; i < 640; i += 256) as[i] = aset[b*640 + i];
    __syncthreads();
    float s = We[651*EE + e] + be[e];
    for (int f = 0; f < 640; ++f) s = fmaf(as[f], We[f*EE + e], s);
    BE[b*EE + e] = s;
}

// ---------------- embedding (8 rows per block), fp32 + packed bf16 ----------
__global__ __launch_bounds__(256) void embed_k(
    const float* __restrict__ BE, const float* __restrict__ ca,
    const float* __restrict__ cr, const float* __restrict__ We,
    const float* __restrict__ be, const float* __restrict__ wpe,
    float* __restrict__ H, ushort* __restrict__ Hbf)
{
    int e = threadIdx.x;
    #pragma unroll
    for (int k = 0; k < 8; ++k) {
        int rb = blockIdx.x * 8 + k;
        int b = rb >> 11, n = rb & (NN-1);
        float h;
        if ((n & 1) == 0) {
            h = BE[b*EE + e];
        } else {
            int t = n >> 1;
            h = We[651*EE + e] + be[e];
            const float* cap = ca + (size_t)(b*TT + t)*10;
            #pragma unroll
            for (int i = 0; i < 10; ++i) h = fmaf(cap[i], We[(640+i)*EE + e], h);
            h = fmaf(cr[b*TT + t], We[650*EE + e], h);
        }
        h = fmaf((float)(n + 1), We[652*EE + e], h);
        h += wpe[(size_t)n*EE + e];
        H[(size_t)rb*EE + e] = h;
        Hbf[pk256(rb, e)] = f2b(h);
    }
}

// ---------------- merged QKV GEMM (packed in, packed out) -------------------
__global__ __launch_bounds__(256, 2) void qkv_k(
    const ushort* __restrict__ A, const ushort* __restrict__ WQK,
    const ushort* __restrict__ WV,
    ushort* __restrict__ Qo, ushort* __restrict__ Ko, ushort* __restrict__ Vo)
{
    int tid = threadIdx.x;
    int w = tid >> 6, l = tid & 63;
    int lr = l & 15, lg = l >> 4;
    int wr = w >> 1, wc = w & 1;
    int rt0 = blockIdx.x * 8 + wr*4;
    int ct0 = blockIdx.y * 8 + wc*4;
    const ushort* Ap = A + (size_t)rt0*4096 + l*8;
    const ushort* Bp = (blockIdx.y < 4 ? WQK + (size_t)ct0*4096
                                       : WV + (size_t)(ct0-32)*4096) + l*8;
    f32x4 acc[4][4];
    #pragma unroll
    for (int i = 0; i < 4; ++i)
        #pragma unroll
        for (int j = 0; j < 4; ++j) acc[i][j] = (f32x4){0.f,0.f,0.f,0.f};
    #pragma unroll
    for (int kc = 0; kc < 8; ++kc) {
        short8 af[4], bf[4];
        #pragma unroll
        for (int rg = 0; rg < 4; ++rg) af[rg] = *(const short8*)(Ap + (size_t)rg*4096 + kc*512);
        #pragma unroll
        for (int cg = 0; cg < 4; ++cg) bf[cg] = *(const short8*)(Bp + (size_t)cg*4096 + kc*512);
        #pragma unroll
        for (int rg = 0; rg < 4; ++rg)
            #pragma unroll
            for (int cg = 0; cg < 4; ++cg)
                acc[rg][cg] = __builtin_amdgcn_mfma_f32_16x16x32_bf16(af[rg], bf[cg], acc[rg][cg], 0,0,0);
    }
    #pragma unroll
    for (int rg = 0; rg < 4; ++rg)
        #pragma unroll
        for (int cg = 0; cg < 4; ++cg)
            #pragma unroll
            for (int r = 0; r < 4; ++r) {
                int row = rt0*16 + rg*16 + lg*4 + r;
                int col = ct0*16 + cg*16 + lr;
                ushort xv = f2b(acc[rg][cg][r]);
                if (col < 256)      Qo[pk256(row, col)] = xv;
                else if (col < 512) Ko[pk256(row, col - 256)] = xv;
                else {
                    int e = col - 512, bb = row >> 11, nn = row & (NN-1);
                    Vo[vpk_idx(bb, nn, e)] = xv;
                }
            }
}

// ---------------- mlp1: relu(A@W1^T + b1) -> packed -------------------------
__global__ __launch_bounds__(256, 2) void mlp1_k(
    const ushort* __restrict__ A, const ushort* __restrict__ Bw,
    const float* __restrict__ bias, ushort* __restrict__ Cv)
{
    int tid = threadIdx.x;
    int w = tid >> 6, l = tid & 63;
    int lr = l & 15, lg = l >> 4;
    int wr = w >> 1, wc = w & 1;
    int rt0 = blockIdx.x * 8 + wr*4;
    int ct0 = blockIdx.y * 8 + wc*4;
    const ushort* Ap = A  + (size_t)rt0*4096 + l*8;
    const ushort* Bp = Bw + (size_t)ct0*4096 + l*8;
    f32x4 acc[4][4];
    #pragma unroll
    for (int i = 0; i < 4; ++i)
        #pragma unroll
        for (int j = 0; j < 4; ++j) acc[i][j] = (f32x4){0.f,0.f,0.f,0.f};
    #pragma unroll
    for (int kc = 0; kc < 8; ++kc) {
        short8 af[4], bf[4];
        #pragma unroll
        for (int rg = 0; rg < 4; ++rg) af[rg] = *(const short8*)(Ap + (size_t)rg*4096 + kc*512);
        #pragma unroll
        for (int cg = 0; cg < 4; ++cg) bf[cg] = *(const short8*)(Bp + (size_t)cg*4096 + kc*512);
        #pragma unroll
        for (int rg = 0; rg < 4; ++rg)
            #pragma unroll
            for (int cg = 0; cg < 4; ++cg)
                acc[rg][cg] = __builtin_amdgcn_mfma_f32_16x16x32_bf16(af[rg], bf[cg], acc[rg][cg], 0,0,0);
    }
    #pragma unroll
    for (int rg = 0; rg < 4; ++rg)
        #pragma unroll
        for (int cg = 0; cg < 4; ++cg)
            #pragma unroll
            for (int r = 0; r < 4; ++r) {
                int row = rt0*16 + rg*16 + lg*4 + r;
                int col = ct0*16 + cg*16 + lr;
                float x = fmaxf(acc[rg][cg][r] + bias[col], 0.f);
                Cv[pk256(row, col)] = f2b(x);
            }
}

// ---------------- mlp2 + residual + ln2 fused -------------------------------
__global__ __launch_bounds__(256, 2) void mlp2ln_k(
    const ushort* __restrict__ A, const ushort* __restrict__ Bw,
    const float* __restrict__ bias, const float* __restrict__ Res,
    const float* __restrict__ g, const float* __restrict__ bt,
    float* __restrict__ Hout, ushort* __restrict__ Hpk)
{
    int tid = threadIdx.x;
    int w = tid >> 6, l = tid & 63;
    int lr = l & 15, lg = l >> 4;
    int rt0 = blockIdx.x * 2;     // 32 rows
    int ct0 = w * 4;              // 64 cols per wave
    const ushort* Ap = A  + (size_t)rt0*4096 + l*8;
    const ushort* Bp = Bw + (size_t)ct0*4096 + l*8;
    f32x4 acc[2][4];
    #pragma unroll
    for (int i = 0; i < 2; ++i)
        #pragma unroll
        for (int j = 0; j < 4; ++j) acc[i][j] = (f32x4){0.f,0.f,0.f,0.f};
    #pragma unroll
    for (int kc = 0; kc < 8; ++kc) {
        short8 a0 = *(const short8*)(Ap + kc*512);
        short8 a1 = *(const short8*)(Ap + 4096 + kc*512);
        short8 bf[4];
        #pragma unroll
        for (int cg = 0; cg < 4; ++cg) bf[cg] = *(const short8*)(Bp + (size_t)cg*4096 + kc*512);
        #pragma unroll
        for (int cg = 0; cg < 4; ++cg) {
            acc[0][cg] = __builtin_amdgcn_mfma_f32_16x16x32_bf16(a0, bf[cg], acc[0][cg], 0,0,0);
            acc[1][cg] = __builtin_amdgcn_mfma_f32_16x16x32_bf16(a1, bf[cg], acc[1][cg], 0,0,0);
        }
    }
    __shared__ float red[32][4][2];
    float sm[2][4] = {}, sq[2][4] = {};
    #pragma unroll
    for (int rg = 0; rg < 2; ++rg)
        #pragma unroll
        for (int cg = 0; cg < 4; ++cg)
            #pragma unroll
            for (int r = 0; r < 4; ++r) {
                int grow = blockIdx.x*32 + rg*16 + lg*4 + r;
                int col = w*64 + cg*16 + lr;
                float v = acc[rg][cg][r] + bias[col] + Res[(size_t)grow*EE + col];
                acc[rg][cg][r] = v;
                sm[rg][r] += v; sq[rg][r] += v*v;
            }
    #pragma unroll
    for (int off = 1; off < 16; off <<= 1)
        #pragma unroll
        for (int rg = 0; rg < 2; ++rg)
            #pragma unroll
            for (int r = 0; r < 4; ++r) {
                sm[rg][r] += __shfl_xor(sm[rg][r], off);
                sq[rg][r] += __shfl_xor(sq[rg][r], off);
            }
    if (lr == 0) {
        #pragma unroll
        for (int rg = 0; rg < 2; ++rg)
            #pragma unroll
            for (int r = 0; r < 4; ++r) {
                int rl = rg*16 + lg*4 + r;
                red[rl][w][0] = sm[rg][r];
                red[rl][w][1] = sq[rg][r];
            }
    }
    __syncthreads();
    #pragma unroll
    for (int rg = 0; rg < 2; ++rg)
        #pragma unroll
        for (int r = 0; r < 4; ++r) {
            int rl = rg*16 + lg*4 + r;
            float S  = red[rl][0][0] + red[rl][1][0] + red[rl][2][0] + red[rl][3][0];
            float S2 = red[rl][0][1] + red[rl][1][1] + red[rl][2][1] + red[rl][3][1];
            float mean = S * (1.0f/256.0f);
            float var  = S2 * (1.0f/256.0f) - mean*mean;
            float inv  = 1.0f / sqrtf(var + 1e-5f);
            int grow = blockIdx.x*32 + rl;
            #pragma unroll
            for (int cg = 0; cg < 4; ++cg) {
                int col = w*64 + cg*16 + lr;
                float y = (acc[rg][cg][r] - mean) * inv * g[col] + bt[col];
                Hout[(size_t)grow*EE + col] = y;
                Hpk[pk256(grow, col)] = f2b(y);
            }
        }
}

// ---------------- causal relu-attention: LDS-staged tile stream -------------
// 256 blocks = m(0..31) x b(0..7); 128 threads = 2 waves; wave w owns 32-row
// slice z = 2m+w (two 16-row sub-slices sharing K/V frags in registers).
// Both waves walk the SAME jt stream: K(16KB)+V(16KB) double-buffered into
// LDS via global_load_lds (wave 0 stages K, wave 1 stages V); one barrier/iter.
// (128,1) -> full VGPR budget, no spill. Per-wave fused residual+LN1 epilogue.
__global__ __launch_bounds__(128, 1) void attn_k(
    const ushort* __restrict__ Qp, const ushort* __restrict__ Kp,
    const ushort* __restrict__ Vp, const float* __restrict__ H,
    const float* __restrict__ g, const float* __restrict__ bt,
    float* __restrict__ Xout, ushort* __restrict__ Lpk)
{
    int blk = blockIdx.x;            // m*8 + b  (b aligns with XCD)
    int m = blk >> 3, b = blk & 7;
    int tid = threadIdx.x;
    int w = tid >> 6, l = tid & 63;
    int lr = l & 15, lg = l >> 4;
    int z = 2*m + w;                 // this wave's 32-row slice
    int i0 = z * 32;
    int NTw = z + 1;                 // wave's causal j-tiles (32 wide)
    int NTmax = 2*m + 2;             // block loop bound

    __shared__ __align__(16) ushort kv[2][16384];   // 64 KB: [buf][K 8K | V 8K]

    const char* Kgb = (const char*)(Kp + (size_t)(b*128)*4096);
    const char* Vgb = (const char*)(Vp + (size_t)(b*64)*8192);

    // Q for both 16-row sub-slices, in registers
    const ushort* Qt = Qp + (size_t)(b*128 + z*2)*4096 + l*8;
    short8 qa[8], qb2[8];
    #pragma unroll
    for (int kc = 0; kc < 8; ++kc) {
        qa[kc]  = *(const short8*)(Qt + kc*512);
        qb2[kc] = *(const short8*)(Qt + 4096 + kc*512);
    }

    f32x4 oa[16], ob[16];
    #pragma unroll
    for (int et = 0; et < 16; ++et) {
        oa[et] = (f32x4){0.f,0.f,0.f,0.f};
        ob[et] = (f32x4){0.f,0.f,0.f,0.f};
    }

    // stage: wave w stages 16 chunks of 1KB (w=0: K tile, w=1: V tile)
    auto STAGE = [&](int buf, int jt) {
        const char* src0 = (w == 0 ? Kgb : Vgb) + (size_t)jt*16384 + l*16;
        ushort* dst0 = &kv[buf][w*8192];
        #pragma unroll
        for (int i = 0; i < 16; ++i) {
            __builtin_amdgcn_global_load_lds(
                (const __attribute__((address_space(1))) unsigned*)(src0 + i*1024),
                (__attribute__((address_space(3))) unsigned*)(dst0 + i*512),
                16, 0, 0);
        }
    };

    int cur = 0;
    STAGE(0, 0);
    __syncthreads();

    int ig0 = i0 + lr;
    int ig1 = i0 + 16 + lr;
    for (int jt = 0; jt < NTmax; ++jt) {
        if (jt + 1 < NTmax) STAGE(cur ^ 1, jt + 1);
        if (jt < NTw) {
            const ushort* Kt = &kv[cur][0]    + l*8;
            const ushort* Vt = &kv[cur][8192] + l*8;
            // QK^T (swapped), 4 independent chains, shared K frags
            f32x4 c0 = {0.f,0.f,0.f,0.f}, c1 = {0.f,0.f,0.f,0.f};
            f32x4 d0 = {0.f,0.f,0.f,0.f}, d1 = {0.f,0.f,0.f,0.f};
            #pragma unroll
            for (int kc = 0; kc < 8; ++kc) {
                short8 k0 = *(const short8*)(Kt + kc*512);
                short8 k1 = *(const short8*)(Kt + 4096 + kc*512);
                c0 = __builtin_amdgcn_mfma_f32_16x16x32_bf16(k0, qa[kc],  c0, 0,0,0);
                c1 = __builtin_amdgcn_mfma_f32_16x16x32_bf16(k1, qa[kc],  c1, 0,0,0);
                d0 = __builtin_amdgcn_mfma_f32_16x16x32_bf16(k0, qb2[kc], d0, 0,0,0);
                d1 = __builtin_amdgcn_mfma_f32_16x16x32_bf16(k1, qb2[kc], d1, 0,0,0);
            }
            // relu + causal mask (j <= i), both sub-slices
            #pragma unroll
            for (int r = 0; r < 4; ++r) {
                int jg = jt*32 + lg*4 + r;
                c0[r] = (jg <= ig0)      ? fmaxf(c0[r], 0.f) : 0.f;
                c1[r] = (jg + 16 <= ig0) ? fmaxf(c1[r], 0.f) : 0.f;
                d0[r] = (jg <= ig1)      ? fmaxf(d0[r], 0.f) : 0.f;
                d1[r] = (jg + 16 <= ig1) ? fmaxf(d1[r], 0.f) : 0.f;
            }
            int srcA = 32*(lg & 1) + lr;
            int srcB = srcA + 16;
            bool lo = (lg < 2);
            // repack sub-slice 0 -> sa
            unsigned u0 = cvtpk(c0[0], c0[1]), u1 = cvtpk(c0[2], c0[3]);
            unsigned u2 = cvtpk(c1[0], c1[1]), u3 = cvtpk(c1[2], c1[3]);
            unsigned a0A = __shfl((int)u0, srcA), a1A = __shfl((int)u1, srcA);
            unsigned a0B = __shfl((int)u0, srcB), a1B = __shfl((int)u1, srcB);
            unsigned b0A = __shfl((int)u2, srcA), b1A = __shfl((int)u3, srcA);
            unsigned b0B = __shfl((int)u2, srcB), b1B = __shfl((int)u3, srcB);
            union { unsigned u[4]; short8 v; } sv0;
            sv0.u[0] = lo ? a0A : b0A;
            sv0.u[1] = lo ? a1A : b1A;
            sv0.u[2] = lo ? a0B : b0B;
            sv0.u[3] = lo ? a1B : b1B;
            short8 sa = sv0.v;
            // repack sub-slice 1 -> sb
            unsigned v0 = cvtpk(d0[0], d0[1]), v1 = cvtpk(d0[2], d0[3]);
            unsigned v2 = cvtpk(d1[0], d1[1]), v3 = cvtpk(d1[2], d1[3]);
            unsigned c0A = __shfl((int)v0, srcA), c1A = __shfl((int)v1, srcA);
            unsigned c0B = __shfl((int)v0, srcB), c1B = __shfl((int)v1, srcB);
            unsigned d0A = __shfl((int)v2, srcA), d1A = __shfl((int)v3, srcA);
            unsigned d0B = __shfl((int)v2, srcB), d1B = __shfl((int)v3, srcB);
            union { unsigned u[4]; short8 v; } sv1;
            sv1.u[0] = lo ? c0A : d0A;
            sv1.u[1] = lo ? c1A : d1A;
            sv1.u[2] = lo ? c0B : d0B;
            sv1.u[3] = lo ? c1B : d1B;
            short8 sb = sv1.v;
            // PV: both sub-slices share each V fragment
            __builtin_amdgcn_s_setprio(1);
            #pragma unroll
            for (int et = 0; et < 16; ++et) {
                short8 vf = *(const short8*)(Vt + et*512);
                oa[et] = __builtin_amdgcn_mfma_f32_16x16x32_bf16(sa, vf, oa[et], 0,0,0);
                ob[et] = __builtin_amdgcn_mfma_f32_16x16x32_bf16(sb, vf, ob[et], 0,0,0);
            }
            __builtin_amdgcn_s_setprio(0);
        }
        __syncthreads();
        cur ^= 1;
    }

    // ---- per-wave epilogue: residual + 1/(i+1) + LN1, dual output ----
#define EPILOG(SET, OACC)                                                      \
    {                                                                          \
        float sm[4] = {0.f,0.f,0.f,0.f}, sq[4] = {0.f,0.f,0.f,0.f};            \
        _Pragma("unroll")                                                      \
        for (int et = 0; et < 16; ++et)                                        \
            _Pragma("unroll")                                                  \
            for (int r = 0; r < 4; ++r) {                                      \
                int irow = i0 + SET*16 + lg*4 + r;                             \
                size_t base = ((size_t)(b*NN + irow))*EE + et*16 + lr;         \
                float x = H[base] + OACC[et][r] * (1.0f / (float)(irow + 1));  \
                OACC[et][r] = x;                                               \
                sm[r] += x; sq[r] += x*x;                                      \
            }                                                                  \
        _Pragma("unroll")                                                      \
        for (int off = 1; off < 16; off <<= 1)                                 \
            _Pragma("unroll")                                                  \
            for (int r = 0; r < 4; ++r) {                                      \
                sm[r] += __shfl_xor(sm[r], off);                               \
                sq[r] += __shfl_xor(sq[r], off);                               \
            }                                                                  \
        float mean[4], inv[4];                                                 \
        _Pragma("unroll")                                                      \
        for (int r = 0; r < 4; ++r) {                                          \
            mean[r] = sm[r] * (1.0f/256.0f);                                   \
            float var = sq[r] * (1.0f/256.0f) - mean[r]*mean[r];               \
            inv[r] = 1.0f / sqrtf(var + 1e-5f);                                \
        }                                                                      \
        _Pragma("unroll")                                                      \
        for (int et = 0; et < 16; ++et) {                                      \
            int col = et*16 + lr;                                              \
            float gv = g[col], bv = bt[col];                                   \
            _Pragma("unroll")                                                  \
            for (int r = 0; r < 4; ++r) {                                      \
                int irow = i0 + SET*16 + lg*4 + r;                             \
                size_t base = ((size_t)(b*NN + irow))*EE + col;                \
                float y = (OACC[et][r] - mean[r]) * inv[r] * gv + bv;          \
                Xout[base] = y;                                                \
                Lpk[pk256(b*NN + irow, col)] = f2b(y);                         \
            }                                                                  \
        }                                                                      \
    }
    EPILOG(0, oa)
    EPILOG(1, ob)
#undef EPILOG
}

// ---------------- prediction head (even rows only) ----------------
__global__ __launch_bounds__(256) void pred_k(
    const float* __restrict__ H, const float* __restrict__ Wp,
    const float* __restrict__ bp, float* __restrict__ out)
{
    int bt = blockIdx.x;
    int b = bt >> 10, t = bt & 1023;
    size_t row = (size_t)b*NN + 2*t;
    __shared__ float hs[256];
    __shared__ float pr[16][16];
    int tid = threadIdx.x;
    hs[tid] = H[row*EE + tid];
    __syncthreads();
    int c = tid & 15, seg = tid >> 4;
    float p = 0.f;
    if (c < 10) {
        #pragma unroll
        for (int e2 = 0; e2 < 16; ++e2)
            p = fmaf(hs[seg*16 + e2], Wp[(seg*16 + e2)*10 + c], p);
    }
    pr[seg][c] = p;
    __syncthreads();
    if (tid < 10) {
        float sacc = bp[tid];
        #pragma unroll
        for (int k2 = 0; k2 < 16; ++k2) sacc += pr[k2][tid];
        out[(size_t)bt*10 + tid] = sacc;
    }
}

extern "C" void kernel_launch(void* const* d_in, const int* in_sizes, int n_in,
                              void* d_out, int out_size, void* d_ws, size_t ws_size,
                              hipStream_t stream)
{
    const float* action_set = (const float*)d_in[1];
    const float* ctx_act    = (const float*)d_in[2];
    const float* ctx_rew    = (const float*)d_in[3];
    const float* W_embed    = (const float*)d_in[4];
    const float* b_embed    = (const float*)d_in[5];
    const float* wpe        = (const float*)d_in[6];
    const float* Wq         = (const float*)d_in[7];
    const float* Wk         = (const float*)d_in[8];
    const float* Wv         = (const float*)d_in[9];
    const float* ln1g       = (const float*)d_in[10];
    const float* ln1b       = (const float*)d_in[11];
    const float* W1         = (const float*)d_in[12];
    const float* b1         = (const float*)d_in[13];
    const float* W2         = (const float*)d_in[14];
    const float* b2         = (const float*)d_in[15];
    const float* ln2g       = (const float*)d_in[16];
    const float* ln2b       = (const float*)d_in[17];
    const float* Wp         = (const float*)d_in[18];
    const float* bp         = (const float*)d_in[19];
    float* out = (float*)d_out;

    float* ws = (float*)d_ws;
    const size_t SZ = (size_t)BB*NN*EE;   // 4,194,304
    size_t o = 0;
    float*  Hb   = ws;               o += SZ;        // fp32 residual stream
    float*  Xb   = ws + o;           o += SZ;        // fp32 ln1 output
    ushort* Hbf  = (ushort*)(ws+o);  o += SZ/2;      // packed bf16 stream / ln1-packed
    ushort* Qp   = (ushort*)(ws+o);  o += SZ/2;      // packed Q; aliased MLP-mid
    ushort* Kpk  = (ushort*)(ws+o);  o += SZ/2;      // packed K
    ushort* Vpk  = (ushort*)(ws+o);  o += SZ/2;      // packed V
    ushort* WQKt = (ushort*)(ws+o);  o += 262144;
    ushort* WVt  = (ushort*)(ws+o);  o += 131072;
    ushort* W1t  = (ushort*)(ws+o);  o += 131072;
    ushort* W2t  = (ushort*)(ws+o);  o += 131072;
    float*  BE   = ws + o;

    wprep_k<<<320, 256, 0, stream>>>(Wq, Wk, Wv, W1, W2, WQKt, WVt, W1t, W2t);
    base_even_k<<<BB, 256, 0, stream>>>(action_set, W_embed, b_embed, BE);
    embed_k<<<BB*NN/8, 256, 0, stream>>>(BE, ctx_act, ctx_rew, W_embed, b_embed, wpe, Hb, Hbf);

    for (int l = 0; l < LL; ++l) {
        qkv_k<<<dim3(128, 6), 256, 0, stream>>>(
            Hbf, WQKt + (size_t)l*131072, WVt + (size_t)l*65536, Qp, Kpk, Vpk);
        // attn + residual + ln1 -> Xb (fp32) + Hbf (packed; dead input, safe)
        attn_k<<<256, 128, 0, stream>>>(
            Qp, Kpk, Vpk, Hb, ln1g + l*EE, ln1b + l*EE, Xb, Hbf);
        // mlp1: relu(ln1 @ W1 + b1) -> Qp (packed mid)
        mlp1_k<<<dim3(128, 2), 256, 0, stream>>>(
            Hbf, W1t + (size_t)l*65536, b1 + l*EE, Qp);
        // mlp2 + residual(Xb) + ln2 -> Hb (fp32) + Hbf (packed stream)
        mlp2ln_k<<<512, 256, 0, stream>>>(
            Qp, W2t + (size_t)l*65536, b2 + l*EE, Xb,
            ln2g + l*EE, ln2b + l*EE, Hb, Hbf);
    }
    pred_k<<<BB*TT, 256, 0, stream>>>(Hb, Wp, bp, out);
}

// Round 12
// 419.585 us; speedup vs baseline: 1.7278x; 1.7278x over previous
//
#include <hip/hip_runtime.h>

// Transformer_67748814127473 — round 11: R5 base (best measured 446us) with
// mlp1 fused into attn tail (idle combine-waves compute relu(ln1@W1+b1) from
// LDS y-frags; mlp1_k and Lpk global writes deleted).
// B=8, T=1024, N=2048, E=256, L=4.

#define BB 8
#define TT 1024
#define NN 2048
#define EE 256
#define LL 4

typedef __attribute__((ext_vector_type(8))) short short8;
typedef __attribute__((ext_vector_type(4))) float f32x4;

__device__ inline ushort f2b(float f) {
    union { float f; unsigned u; } x; x.f = f;
    unsigned u = x.u;
    return (ushort)((u + 0x7fffu + ((u >> 16) & 1u)) >> 16);
}
__device__ inline unsigned cvtpk(float lo, float hi) {
    unsigned r;
    asm volatile("v_cvt_pk_bf16_f32 %0, %1, %2" : "=v"(r) : "v"(lo), "v"(hi));
    return r;
}
// fragment-linear pack for K=256 operands: tile16(row) x kchunk32 -> [lane][8]
__device__ inline size_t pk256(int row, int k) {
    return ((size_t)((row >> 4) * 8 + (k >> 5))) * 512
         + (size_t)((((k >> 3) & 3) * 16 + (row & 15)) * 8 + (k & 7));
}
// V pack: (batch, token n, embed e) -> B-frag linear
__device__ inline size_t vpk_idx(int bb, int nn, int e) {
    return ((size_t)(bb*64 + (nn >> 5)) * 16 + (e >> 4)) * 512
         + (size_t)((((nn >> 3) & 3) * 16 + (e & 15)) * 8 + (nn & 7));
}

// ---------------- weight prep: transpose + cast + frag-pack ----------------
__global__ __launch_bounds__(256) void wprep_k(
    const float* __restrict__ Wq, const float* __restrict__ Wk,
    const float* __restrict__ Wv, const float* __restrict__ W1,
    const float* __restrict__ W2,
    ushort* __restrict__ WQKt, ushort* __restrict__ WVt,
    ushort* __restrict__ W1t, ushort* __restrict__ W2t)
{
    int id = blockIdx.x;          // 320 = 20 matrices x 16 tiles
    int m = id >> 4, t = id & 15;
    int l = m / 5, which = m % 5;
    const float* src; ushort* dst;
    size_t o = (size_t)l * 65536;
    switch (which) {
        case 0: src = Wq + o; dst = WQKt + (size_t)l*131072;          break;
        case 1: src = Wk + o; dst = WQKt + (size_t)l*131072 + 65536;  break;
        case 2: src = Wv + o; dst = WVt + o; break;
        case 3: src = W1 + o; dst = W1t + o; break;
        default: src = W2 + o; dst = W2t + o; break;
    }
    int tk = (t >> 2) * 64;   // k block
    int tn = (t & 3) * 64;    // n block (output col)
    __shared__ ushort T[64][68];
    int tid = threadIdx.x;
    int r = tid >> 4, c4 = (tid & 15) * 4;
    #pragma unroll
    for (int it = 0; it < 4; ++it) {
        int k = r + it*16;
        float4 v = *(const float4*)&src[(size_t)(tk + k)*256 + tn + c4];
        T[k][c4+0] = f2b(v.x); T[k][c4+1] = f2b(v.y);
        T[k][c4+2] = f2b(v.z); T[k][c4+3] = f2b(v.w);
    }
    __syncthreads();
    #pragma unroll
    for (int it = 0; it < 4; ++it) {
        int n = tn + r + it*16;
        int k0 = tk + c4;
        ushort4 ov;
        ov.x = T[c4+0][n-tn]; ov.y = T[c4+1][n-tn];
        ov.z = T[c4+2][n-tn]; ov.w = T[c4+3][n-tn];
        *(ushort4*)&dst[pk256(n, k0)] = ov;
    }
}

// ---------------- per-batch even-row base vector ----------------
__global__ __launch_bounds__(256) void base_even_k(
    const float* __restrict__ aset, const float* __restrict__ We,
    const float* __restrict__ be, float* __restrict__ BE)
{
    int b = blockIdx.x; int e = threadIdx.x;
    __shared__ float as[640];
    for (int i = e; i < 640; i += 256) as[i] = aset[b*640 + i];
    __syncthreads();
    float s = We[651*EE + e] + be[e];
    for (int f = 0; f < 640; ++f) s = fmaf(as[f], We[f*EE + e], s);
    BE[b*EE + e] = s;
}

// ---------------- embedding (8 rows per block), fp32 + packed bf16 ----------
__global__ __launch_bounds__(256) void embed_k(
    const float* __restrict__ BE, const float* __restrict__ ca,
    const float* __restrict__ cr, const float* __restrict__ We,
    const float* __restrict__ be, const float* __restrict__ wpe,
    float* __restrict__ H, ushort* __restrict__ Hbf)
{
    int e = threadIdx.x;
    #pragma unroll
    for (int k = 0; k < 8; ++k) {
        int rb = blockIdx.x * 8 + k;
        int b = rb >> 11, n = rb & (NN-1);
        float h;
        if ((n & 1) == 0) {
            h = BE[b*EE + e];
        } else {
            int t = n >> 1;
            h = We[651*EE + e] + be[e];
            const float* cap = ca + (size_t)(b*TT + t)*10;
            #pragma unroll
            for (int i = 0; i < 10; ++i) h = fmaf(cap[i], We[(640+i)*EE + e], h);
            h = fmaf(cr[b*TT + t], We[650*EE + e], h);
        }
        h = fmaf((float)(n + 1), We[652*EE + e], h);
        h += wpe[(size_t)n*EE + e];
        H[(size_t)rb*EE + e] = h;
        Hbf[pk256(rb, e)] = f2b(h);
    }
}

// ---------------- merged QKV GEMM (packed in, packed out) -------------------
__global__ __launch_bounds__(256, 2) void qkv_k(
    const ushort* __restrict__ A, const ushort* __restrict__ WQK,
    const ushort* __restrict__ WV,
    ushort* __restrict__ Qo, ushort* __restrict__ Ko, ushort* __restrict__ Vo)
{
    int tid = threadIdx.x;
    int w = tid >> 6, l = tid & 63;
    int lr = l & 15, lg = l >> 4;
    int wr = w >> 1, wc = w & 1;
    int rt0 = blockIdx.x * 8 + wr*4;
    int ct0 = blockIdx.y * 8 + wc*4;
    const ushort* Ap = A + (size_t)rt0*4096 + l*8;
    const ushort* Bp = (blockIdx.y < 4 ? WQK + (size_t)ct0*4096
                                       : WV + (size_t)(ct0-32)*4096) + l*8;
    f32x4 acc[4][4];
    #pragma unroll
    for (int i = 0; i < 4; ++i)
        #pragma unroll
        for (int j = 0; j < 4; ++j) acc[i][j] = (f32x4){0.f,0.f,0.f,0.f};
    #pragma unroll
    for (int kc = 0; kc < 8; ++kc) {
        short8 af[4], bf[4];
        #pragma unroll
        for (int rg = 0; rg < 4; ++rg) af[rg] = *(const short8*)(Ap + (size_t)rg*4096 + kc*512);
        #pragma unroll
        for (int cg = 0; cg < 4; ++cg) bf[cg] = *(const short8*)(Bp + (size_t)cg*4096 + kc*512);
        #pragma unroll
        for (int rg = 0; rg < 4; ++rg)
            #pragma unroll
            for (int cg = 0; cg < 4; ++cg)
                acc[rg][cg] = __builtin_amdgcn_mfma_f32_16x16x32_bf16(af[rg], bf[cg], acc[rg][cg], 0,0,0);
    }
    #pragma unroll
    for (int rg = 0; rg < 4; ++rg)
        #pragma unroll
        for (int cg = 0; cg < 4; ++cg)
            #pragma unroll
            for (int r = 0; r < 4; ++r) {
                int row = rt0*16 + rg*16 + lg*4 + r;
                int col = ct0*16 + cg*16 + lr;
                ushort xv = f2b(acc[rg][cg][r]);
                if (col < 256)      Qo[pk256(row, col)] = xv;
                else if (col < 512) Ko[pk256(row, col - 256)] = xv;
                else {
                    int e = col - 512, bb = row >> 11, nn = row & (NN-1);
                    Vo[vpk_idx(bb, nn, e)] = xv;
                }
            }
}

// ---------------- mlp2 + residual + ln2 fused -------------------------------
__global__ __launch_bounds__(256, 2) void mlp2ln_k(
    const ushort* __restrict__ A, const ushort* __restrict__ Bw,
    const float* __restrict__ bias, const float* __restrict__ Res,
    const float* __restrict__ g, const float* __restrict__ bt,
    float* __restrict__ Hout, ushort* __restrict__ Hpk)
{
    int tid = threadIdx.x;
    int w = tid >> 6, l = tid & 63;
    int lr = l & 15, lg = l >> 4;
    int rt0 = blockIdx.x * 2;     // 32 rows
    int ct0 = w * 4;              // 64 cols per wave
    const ushort* Ap = A  + (size_t)rt0*4096 + l*8;
    const ushort* Bp = Bw + (size_t)ct0*4096 + l*8;
    f32x4 acc[2][4];
    #pragma unroll
    for (int i = 0; i < 2; ++i)
        #pragma unroll
        for (int j = 0; j < 4; ++j) acc[i][j] = (f32x4){0.f,0.f,0.f,0.f};
    #pragma unroll
    for (int kc = 0; kc < 8; ++kc) {
        short8 a0 = *(const short8*)(Ap + kc*512);
        short8 a1 = *(const short8*)(Ap + 4096 + kc*512);
        short8 bf[4];
        #pragma unroll
        for (int cg = 0; cg < 4; ++cg) bf[cg] = *(const short8*)(Bp + (size_t)cg*4096 + kc*512);
        #pragma unroll
        for (int cg = 0; cg < 4; ++cg) {
            acc[0][cg] = __builtin_amdgcn_mfma_f32_16x16x32_bf16(a0, bf[cg], acc[0][cg], 0,0,0);
            acc[1][cg] = __builtin_amdgcn_mfma_f32_16x16x32_bf16(a1, bf[cg], acc[1][cg], 0,0,0);
        }
    }
    __shared__ float red[32][4][2];
    float sm[2][4] = {}, sq[2][4] = {};
    #pragma unroll
    for (int rg = 0; rg < 2; ++rg)
        #pragma unroll
        for (int cg = 0; cg < 4; ++cg)
            #pragma unroll
            for (int r = 0; r < 4; ++r) {
                int grow = blockIdx.x*32 + rg*16 + lg*4 + r;
                int col = w*64 + cg*16 + lr;
                float v = acc[rg][cg][r] + bias[col] + Res[(size_t)grow*EE + col];
                acc[rg][cg][r] = v;
                sm[rg][r] += v; sq[rg][r] += v*v;
            }
    #pragma unroll
    for (int off = 1; off < 16; off <<= 1)
        #pragma unroll
        for (int rg = 0; rg < 2; ++rg)
            #pragma unroll
            for (int r = 0; r < 4; ++r) {
                sm[rg][r] += __shfl_xor(sm[rg][r], off);
                sq[rg][r] += __shfl_xor(sq[rg][r], off);
            }
    if (lr == 0) {
        #pragma unroll
        for (int rg = 0; rg < 2; ++rg)
            #pragma unroll
            for (int r = 0; r < 4; ++r) {
                int rl = rg*16 + lg*4 + r;
                red[rl][w][0] = sm[rg][r];
                red[rl][w][1] = sq[rg][r];
            }
    }
    __syncthreads();
    #pragma unroll
    for (int rg = 0; rg < 2; ++rg)
        #pragma unroll
        for (int r = 0; r < 4; ++r) {
            int rl = rg*16 + lg*4 + r;
            float S  = red[rl][0][0] + red[rl][1][0] + red[rl][2][0] + red[rl][3][0];
            float S2 = red[rl][0][1] + red[rl][1][1] + red[rl][2][1] + red[rl][3][1];
            float mean = S * (1.0f/256.0f);
            float var  = S2 * (1.0f/256.0f) - mean*mean;
            float inv  = 1.0f / sqrtf(var + 1e-5f);
            int grow = blockIdx.x*32 + rl;
            #pragma unroll
            for (int cg = 0; cg < 4; ++cg) {
                int col = w*64 + cg*16 + lr;
                float y = (acc[rg][cg][r] - mean) * inv * g[col] + bt[col];
                Hout[(size_t)grow*EE + col] = y;
                Hpk[pk256(grow, col)] = f2b(y);
            }
        }
}

// ---------------- attention + ln1 + FUSED mlp1 ----------------
// R5 structure (verified): 512 blocks = 64 slice-pairs (s,127-s) x 8 batches;
// 8 waves = 2 slices x 4 j-quarters; register-only S via swapped MFMA +
// cvt_pk/shfl repack; 4-way LDS combine; part-0 epilogue computes
// x = H + O/(i+1), y = LN1(x) -> Xout (fp32) and LDS y-frags (bf16).
// NEW tail: barrier, then all 8 waves compute mid = relu(y@W1^T+b1) from
// LDS A-frags + L2-hot W1 B-frags, write packed mid into Qp (own rows only).
__global__ __launch_bounds__(512, 2) void attn_k(
    const ushort* Qp, const ushort* __restrict__ Kp,
    const ushort* __restrict__ Vp, const float* __restrict__ H,
    const float* __restrict__ g, const float* __restrict__ bt,
    const ushort* __restrict__ W1t, const float* __restrict__ b1p,
    float* __restrict__ Xout, ushort* Mid)
{
    int blk = blockIdx.x;            // pk*8 + b
    int pk = blk >> 3, b = blk & 7;
    int tid = threadIdx.x;
    int w = tid >> 6, l = tid & 63;
    int lr = l & 15, lg = l >> 4;
    int sel  = (w & 1) ^ ((w >> 2) & 1);
    int part = w >> 1;
    int s  = sel ? (127 - pk) : pk;  // 16-row slice index within batch
    int i0 = s * 16;
    int NT = (s >> 1) + 1;           // causal j-tiles of 32
    int j0 = (part * NT) >> 2;
    int j1 = ((part + 1) * NT) >> 2;

    __shared__ float comb[2][5440];      // 43.5 KB combine
    __shared__ ushort ylds[2][4096];     // 16 KB: per-slice y frag-pack

    const ushort* Qt    = Qp + ((size_t)(b*128 + s)) * 4096 + l*8;
    const ushort* Kbase = Kp + (size_t)(b*128) * 4096 + l*8;
    const ushort* Vbase = Vp + (size_t)(b*64) * 16 * 512 + l*8;

    short8 qb[8];
    #pragma unroll
    for (int kc = 0; kc < 8; ++kc) qb[kc] = *(const short8*)(Qt + kc*512);

    f32x4 oacc[16];
    #pragma unroll
    for (int et = 0; et < 16; ++et) oacc[et] = (f32x4){0.f,0.f,0.f,0.f};

    int ig = i0 + lr;
    for (int jt = j0; jt < j1; ++jt) {
        const ushort* Kt = Kbase + (size_t)(jt*2) * 4096;
        short8 ka0[8], ka1[8];
        #pragma unroll
        for (int kc = 0; kc < 8; ++kc) {
            ka0[kc] = *(const short8*)(Kt + kc*512);
            ka1[kc] = *(const short8*)(Kt + 4096 + kc*512);
        }
        const ushort* Vt = Vbase + (size_t)(jt*16) * 512;
        short8 vf[16];
        #pragma unroll
        for (int et = 0; et < 16; ++et)
            vf[et] = *(const short8*)(Vt + et*512);
        // QK^T (swapped), 4 independent chains
        f32x4 c0a = {0.f,0.f,0.f,0.f}, c0b = {0.f,0.f,0.f,0.f};
        f32x4 c1a = {0.f,0.f,0.f,0.f}, c1b = {0.f,0.f,0.f,0.f};
        #pragma unroll
        for (int kc = 0; kc < 8; kc += 2) {
            c0a = __builtin_amdgcn_mfma_f32_16x16x32_bf16(ka0[kc],   qb[kc],   c0a, 0,0,0);
            c0b = __builtin_amdgcn_mfma_f32_16x16x32_bf16(ka0[kc+1], qb[kc+1], c0b, 0,0,0);
            c1a = __builtin_amdgcn_mfma_f32_16x16x32_bf16(ka1[kc],   qb[kc],   c1a, 0,0,0);
            c1b = __builtin_amdgcn_mfma_f32_16x16x32_bf16(ka1[kc+1], qb[kc+1], c1b, 0,0,0);
        }
        f32x4 c0 = c0a + c0b, c1 = c1a + c1b;
        // relu + causal mask (j <= i)
        #pragma unroll
        for (int r = 0; r < 4; ++r) {
            int jg = jt*32 + lg*4 + r;
            c0[r] = (jg <= ig) ? fmaxf(c0[r], 0.f) : 0.f;
            c1[r] = (jg + 16 <= ig) ? fmaxf(c1[r], 0.f) : 0.f;
        }
        // pack to bf16 pairs and repack C-layout -> PV A-frag via shfl
        unsigned u0 = cvtpk(c0[0], c0[1]), u1 = cvtpk(c0[2], c0[3]);
        unsigned u2 = cvtpk(c1[0], c1[1]), u3 = cvtpk(c1[2], c1[3]);
        int srcA = 32*(lg & 1) + lr;
        int srcB = srcA + 16;
        unsigned a0A = __shfl((int)u0, srcA), a1A = __shfl((int)u1, srcA);
        unsigned a0B = __shfl((int)u0, srcB), a1B = __shfl((int)u1, srcB);
        unsigned b0A = __shfl((int)u2, srcA), b1A = __shfl((int)u3, srcA);
        unsigned b0B = __shfl((int)u2, srcB), b1B = __shfl((int)u3, srcB);
        bool lo = (lg < 2);
        union { unsigned u[4]; short8 v; } sv;
        sv.u[0] = lo ? a0A : b0A;
        sv.u[1] = lo ? a1A : b1A;
        sv.u[2] = lo ? a0B : b0B;
        sv.u[3] = lo ? a1B : b1B;
        short8 sa = sv.v;
        // PV: O[16][256] += S @ V_jt
        __builtin_amdgcn_s_setprio(1);
        #pragma unroll
        for (int et = 0; et < 16; ++et)
            oacc[et] = __builtin_amdgcn_mfma_f32_16x16x32_bf16(sa, vf[et], oacc[et], 0,0,0);
        __builtin_amdgcn_s_setprio(0);
    }

    // ---- 4-way combine (parts 1..3 -> LDS) ----
    float* cb = &comb[sel][0];
    #pragma unroll
    for (int rnd = 1; rnd <= 3; ++rnd) {
        if (part == rnd) {
            #pragma unroll
            for (int et = 0; et < 16; ++et)
                #pragma unroll
                for (int r = 0; r < 4; ++r) {
                    int idx = et*340 + l*5 + r;
                    float v = oacc[et][r];
                    if (rnd == 1) cb[idx] = v; else cb[idx] += v;
                }
        }
        __syncthreads();
    }
    // ---- epilogue by part 0: residual + scale + LN1 -> Xout + LDS y-frags --
    if (part == 0) {
        float sm[4] = {0.f,0.f,0.f,0.f}, sq[4] = {0.f,0.f,0.f,0.f};
        #pragma unroll
        for (int et = 0; et < 16; ++et)
            #pragma unroll
            for (int r = 0; r < 4; ++r) {
                int irow = i0 + lg*4 + r;
                size_t base = ((size_t)(b*NN + irow))*EE + et*16 + lr;
                float x = H[base] + (oacc[et][r] + cb[et*340 + l*5 + r])
                                    * (1.0f / (float)(irow + 1));
                oacc[et][r] = x;
                sm[r] += x; sq[r] += x*x;
            }
        #pragma unroll
        for (int off = 1; off < 16; off <<= 1)
            #pragma unroll
            for (int r = 0; r < 4; ++r) {
                sm[r] += __shfl_xor(sm[r], off);
                sq[r] += __shfl_xor(sq[r], off);
            }
        float mean[4], inv[4];
        #pragma unroll
        for (int r = 0; r < 4; ++r) {
            mean[r] = sm[r] * (1.0f/256.0f);
            float var = sq[r] * (1.0f/256.0f) - mean[r]*mean[r];
            inv[r] = 1.0f / sqrtf(var + 1e-5f);
        }
        ushort* yl = &ylds[sel][0];
        #pragma unroll
        for (int et = 0; et < 16; ++et) {
            int col = et*16 + lr;
            float gv = g[col], bv = bt[col];
            #pragma unroll
            for (int r = 0; r < 4; ++r) {
                int irow = i0 + lg*4 + r;
                size_t base = ((size_t)(b*NN + irow))*EE + col;
                float y = (oacc[et][r] - mean[r]) * inv[r] * gv + bv;
                Xout[base] = y;
                // scatter into pk-frag layout: kc = col>>5
                int idx = (col >> 5)*512 + ((((col >> 3) & 3) << 4) + lg*4 + r)*8
                        + (col & 7);
                yl[idx] = f2b(y);
            }
        }
    }
    __syncthreads();
    // ---- fused mlp1: all 8 waves; wave = (slice sel, 64-col group part) ----
    {
        const ushort* Ay = &ylds[sel][0] + l*8;
        const ushort* Bp = W1t + (size_t)(part*4)*4096 + l*8;
        f32x4 macc[4];
        #pragma unroll
        for (int cg = 0; cg < 4; ++cg) macc[cg] = (f32x4){0.f,0.f,0.f,0.f};
        #pragma unroll
        for (int kc = 0; kc < 8; ++kc) {
            short8 af = *(const short8*)(Ay + kc*512);
            #pragma unroll
            for (int cg = 0; cg < 4; ++cg) {
                short8 bf = *(const short8*)(Bp + (size_t)cg*4096 + kc*512);
                macc[cg] = __builtin_amdgcn_mfma_f32_16x16x32_bf16(af, bf, macc[cg], 0,0,0);
            }
        }
        #pragma unroll
        for (int cg = 0; cg < 4; ++cg)
            #pragma unroll
            for (int r = 0; r < 4; ++r) {
                int row = i0 + lg*4 + r;
                int col = part*64 + cg*16 + lr;
                float x = fmaxf(macc[cg][r] + b1p[col], 0.f);
                Mid[pk256(b*NN + row, col)] = f2b(x);
            }
    }
}

// ---------------- prediction head (even rows only) ----------------
__global__ __launch_bounds__(256) void pred_k(
    const float* __restrict__ H, const float* __restrict__ Wp,
    const float* __restrict__ bp, float* __restrict__ out)
{
    int bt = blockIdx.x;
    int b = bt >> 10, t = bt & 1023;
    size_t row = (size_t)b*NN + 2*t;
    __shared__ float hs[256];
    __shared__ float pr[16][16];
    int tid = threadIdx.x;
    hs[tid] = H[row*EE + tid];
    __syncthreads();
    int c = tid & 15, seg = tid >> 4;
    float p = 0.f;
    if (c < 10) {
        #pragma unroll
        for (int e2 = 0; e2 < 16; ++e2)
            p = fmaf(hs[seg*16 + e2], Wp[(seg*16 + e2)*10 + c], p);
    }
    pr[seg][c] = p;
    __syncthreads();
    if (tid < 10) {
        float sacc = bp[tid];
        #pragma unroll
        for (int k2 = 0; k2 < 16; ++k2) sacc += pr[k2][tid];
        out[(size_t)bt*10 + tid] = sacc;
    }
}

extern "C" void kernel_launch(void* const* d_in, const int* in_sizes, int n_in,
                              void* d_out, int out_size, void* d_ws, size_t ws_size,
                              hipStream_t stream)
{
    const float* action_set = (const float*)d_in[1];
    const float* ctx_act    = (const float*)d_in[2];
    const float* ctx_rew    = (const float*)d_in[3];
    const float* W_embed    = (const float*)d_in[4];
    const float* b_embed    = (const float*)d_in[5];
    const float* wpe        = (const float*)d_in[6];
    const float* Wq         = (const float*)d_in[7];
    const float* Wk         = (const float*)d_in[8];
    const float* Wv         = (const float*)d_in[9];
    const float* ln1g       = (const float*)d_in[10];
    const float* ln1b       = (const float*)d_in[11];
    const float* W1         = (const float*)d_in[12];
    const float* b1         = (const float*)d_in[13];
    const float* W2         = (const float*)d_in[14];
    const float* b2         = (const float*)d_in[15];
    const float* ln2g       = (const float*)d_in[16];
    const float* ln2b       = (const float*)d_in[17];
    const float* Wp         = (const float*)d_in[18];
    const float* bp         = (const float*)d_in[19];
    float* out = (float*)d_out;

    float* ws = (float*)d_ws;
    const size_t SZ = (size_t)BB*NN*EE;   // 4,194,304
    size_t o = 0;
    float*  Hb   = ws;               o += SZ;        // fp32 residual stream
    float*  Xb   = ws + o;           o += SZ;        // fp32 ln1 output
    ushort* Hbf  = (ushort*)(ws+o);  o += SZ/2;      // packed bf16 stream
    ushort* Qp   = (ushort*)(ws+o);  o += SZ/2;      // packed Q; becomes mid
    ushort* Kpk  = (ushort*)(ws+o);  o += SZ/2;      // packed K
    ushort* Vpk  = (ushort*)(ws+o);  o += SZ/2;      // packed V
    ushort* WQKt = (ushort*)(ws+o);  o += 262144;
    ushort* WVt  = (ushort*)(ws+o);  o += 131072;
    ushort* W1t  = (ushort*)(ws+o);  o += 131072;
    ushort* W2t  = (ushort*)(ws+o);  o += 131072;
    float*  BE   = ws + o;

    wprep_k<<<320, 256, 0, stream>>>(Wq, Wk, Wv, W1, W2, WQKt, WVt, W1t, W2t);
    base_even_k<<<BB, 256, 0, stream>>>(action_set, W_embed, b_embed, BE);
    embed_k<<<BB*NN/8, 256, 0, stream>>>(BE, ctx_act, ctx_rew, W_embed, b_embed, wpe, Hb, Hbf);

    for (int l = 0; l < LL; ++l) {
        qkv_k<<<dim3(128, 6), 256, 0, stream>>>(
            Hbf, WQKt + (size_t)l*131072, WVt + (size_t)l*65536, Qp, Kpk, Vpk);
        // attn + residual + ln1 + mlp1 -> Xb (fp32 ln1) + Qp (packed mid)
        attn_k<<<512, 512, 0, stream>>>(
            Qp, Kpk, Vpk, Hb, ln1g + l*EE, ln1b + l*EE,
            W1t + (size_t)l*65536, b1 + l*EE, Xb, Qp);
        // mlp2 + residual(Xb) + ln2 -> Hb (fp32) + Hbf (packed stream)
        mlp2ln_k<<<512, 256, 0, stream>>>(
            Qp, W2t + (size_t)l*65536, b2 + l*EE, Xb,
            ln2g + l*EE, ln2b + l*EE, Hb, Hbf);
    }
    pred_k<<<BB*TT, 256, 0, stream>>>(Hb, Wp, bp, out);
}

// Round 13
// 399.555 us; speedup vs baseline: 1.8144x; 1.0501x over previous
//
#include <hip/hip_runtime.h>

// Transformer_67748814127473 — round 12: full layer-tail fusion. attn_k now
// computes attn + ln1 + mlp1 + mlp2 + residual + ln2 (entire post-QKV layer):
// y fp32 kept in comb LDS, mid exchanged through ylds, ln2 via 1KB red LDS.
// mlp2ln_k deleted; 2 dispatches/layer. B=8, T=1024, N=2048, E=256, L=4.

#define BB 8
#define TT 1024
#define NN 2048
#define EE 256
#define LL 4

typedef __attribute__((ext_vector_type(8))) short short8;
typedef __attribute__((ext_vector_type(4))) float f32x4;

__device__ inline ushort f2b(float f) {
    union { float f; unsigned u; } x; x.f = f;
    unsigned u = x.u;
    return (ushort)((u + 0x7fffu + ((u >> 16) & 1u)) >> 16);
}
__device__ inline unsigned cvtpk(float lo, float hi) {
    unsigned r;
    asm volatile("v_cvt_pk_bf16_f32 %0, %1, %2" : "=v"(r) : "v"(lo), "v"(hi));
    return r;
}
// fragment-linear pack for K=256 operands: tile16(row) x kchunk32 -> [lane][8]
__device__ inline size_t pk256(int row, int k) {
    return ((size_t)((row >> 4) * 8 + (k >> 5))) * 512
         + (size_t)((((k >> 3) & 3) * 16 + (row & 15)) * 8 + (k & 7));
}
// V pack: (batch, token n, embed e) -> B-frag linear
__device__ inline size_t vpk_idx(int bb, int nn, int e) {
    return ((size_t)(bb*64 + (nn >> 5)) * 16 + (e >> 4)) * 512
         + (size_t)((((nn >> 3) & 3) * 16 + (e & 15)) * 8 + (nn & 7));
}

// ---------------- weight prep: transpose + cast + frag-pack ----------------
__global__ __launch_bounds__(256) void wprep_k(
    const float* __restrict__ Wq, const float* __restrict__ Wk,
    const float* __restrict__ Wv, const float* __restrict__ W1,
    const float* __restrict__ W2,
    ushort* __restrict__ WQKt, ushort* __restrict__ WVt,
    ushort* __restrict__ W1t, ushort* __restrict__ W2t)
{
    int id = blockIdx.x;          // 320 = 20 matrices x 16 tiles
    int m = id >> 4, t = id & 15;
    int l = m / 5, which = m % 5;
    const float* src; ushort* dst;
    size_t o = (size_t)l * 65536;
    switch (which) {
        case 0: src = Wq + o; dst = WQKt + (size_t)l*131072;          break;
        case 1: src = Wk + o; dst = WQKt + (size_t)l*131072 + 65536;  break;
        case 2: src = Wv + o; dst = WVt + o; break;
        case 3: src = W1 + o; dst = W1t + o; break;
        default: src = W2 + o; dst = W2t + o; break;
    }
    int tk = (t >> 2) * 64;   // k block
    int tn = (t & 3) * 64;    // n block (output col)
    __shared__ ushort T[64][68];
    int tid = threadIdx.x;
    int r = tid >> 4, c4 = (tid & 15) * 4;
    #pragma unroll
    for (int it = 0; it < 4; ++it) {
        int k = r + it*16;
        float4 v = *(const float4*)&src[(size_t)(tk + k)*256 + tn + c4];
        T[k][c4+0] = f2b(v.x); T[k][c4+1] = f2b(v.y);
        T[k][c4+2] = f2b(v.z); T[k][c4+3] = f2b(v.w);
    }
    __syncthreads();
    #pragma unroll
    for (int it = 0; it < 4; ++it) {
        int n = tn + r + it*16;
        int k0 = tk + c4;
        ushort4 ov;
        ov.x = T[c4+0][n-tn]; ov.y = T[c4+1][n-tn];
        ov.z = T[c4+2][n-tn]; ov.w = T[c4+3][n-tn];
        *(ushort4*)&dst[pk256(n, k0)] = ov;
    }
}

// ---------------- per-batch even-row base vector ----------------
__global__ __launch_bounds__(256) void base_even_k(
    const float* __restrict__ aset, const float* __restrict__ We,
    const float* __restrict__ be, float* __restrict__ BE)
{
    int b = blockIdx.x; int e = threadIdx.x;
    __shared__ float as[640];
    for (int i = e; i < 640; i += 256) as[i] = aset[b*640 + i];
    __syncthreads();
    float s = We[651*EE + e] + be[e];
    for (int f = 0; f < 640; ++f) s = fmaf(as[f], We[f*EE + e], s);
    BE[b*EE + e] = s;
}

// ---------------- embedding (8 rows per block), fp32 + packed bf16 ----------
__global__ __launch_bounds__(256) void embed_k(
    const float* __restrict__ BE, const float* __restrict__ ca,
    const float* __restrict__ cr, const float* __restrict__ We,
    const float* __restrict__ be, const float* __restrict__ wpe,
    float* __restrict__ H, ushort* __restrict__ Hbf)
{
    int e = threadIdx.x;
    #pragma unroll
    for (int k = 0; k < 8; ++k) {
        int rb = blockIdx.x * 8 + k;
        int b = rb >> 11, n = rb & (NN-1);
        float h;
        if ((n & 1) == 0) {
            h = BE[b*EE + e];
        } else {
            int t = n >> 1;
            h = We[651*EE + e] + be[e];
            const float* cap = ca + (size_t)(b*TT + t)*10;
            #pragma unroll
            for (int i = 0; i < 10; ++i) h = fmaf(cap[i], We[(640+i)*EE + e], h);
            h = fmaf(cr[b*TT + t], We[650*EE + e], h);
        }
        h = fmaf((float)(n + 1), We[652*EE + e], h);
        h += wpe[(size_t)n*EE + e];
        H[(size_t)rb*EE + e] = h;
        Hbf[pk256(rb, e)] = f2b(h);
    }
}

// ---------------- merged QKV GEMM (packed in, packed out) -------------------
__global__ __launch_bounds__(256, 2) void qkv_k(
    const ushort* __restrict__ A, const ushort* __restrict__ WQK,
    const ushort* __restrict__ WV,
    ushort* __restrict__ Qo, ushort* __restrict__ Ko, ushort* __restrict__ Vo)
{
    int tid = threadIdx.x;
    int w = tid >> 6, l = tid & 63;
    int lr = l & 15, lg = l >> 4;
    int wr = w >> 1, wc = w & 1;
    int rt0 = blockIdx.x * 8 + wr*4;
    int ct0 = blockIdx.y * 8 + wc*4;
    const ushort* Ap = A + (size_t)rt0*4096 + l*8;
    const ushort* Bp = (blockIdx.y < 4 ? WQK + (size_t)ct0*4096
                                       : WV + (size_t)(ct0-32)*4096) + l*8;
    f32x4 acc[4][4];
    #pragma unroll
    for (int i = 0; i < 4; ++i)
        #pragma unroll
        for (int j = 0; j < 4; ++j) acc[i][j] = (f32x4){0.f,0.f,0.f,0.f};
    #pragma unroll
    for (int kc = 0; kc < 8; ++kc) {
        short8 af[4], bf[4];
        #pragma unroll
        for (int rg = 0; rg < 4; ++rg) af[rg] = *(const short8*)(Ap + (size_t)rg*4096 + kc*512);
        #pragma unroll
        for (int cg = 0; cg < 4; ++cg) bf[cg] = *(const short8*)(Bp + (size_t)cg*4096 + kc*512);
        #pragma unroll
        for (int rg = 0; rg < 4; ++rg)
            #pragma unroll
            for (int cg = 0; cg < 4; ++cg)
                acc[rg][cg] = __builtin_amdgcn_mfma_f32_16x16x32_bf16(af[rg], bf[cg], acc[rg][cg], 0,0,0);
    }
    #pragma unroll
    for (int rg = 0; rg < 4; ++rg)
        #pragma unroll
        for (int cg = 0; cg < 4; ++cg)
            #pragma unroll
            for (int r = 0; r < 4; ++r) {
                int row = rt0*16 + rg*16 + lg*4 + r;
                int col = ct0*16 + cg*16 + lr;
                ushort xv = f2b(acc[rg][cg][r]);
                if (col < 256)      Qo[pk256(row, col)] = xv;
                else if (col < 512) Ko[pk256(row, col - 256)] = xv;
                else {
                    int e = col - 512, bb = row >> 11, nn = row & (NN-1);
                    Vo[vpk_idx(bb, nn, e)] = xv;
                }
            }
}

// ---------------- attention + ln1 + mlp1 + mlp2 + ln2 (full layer tail) -----
// R5/R11 structure: 512 blocks = 64 slice-pairs (s,127-s) x 8 batches;
// 8 waves = 2 slices x 4 j-quarters; register-only S; 4-way LDS combine;
// part-0 epilogue: x = H + O/(i+1), y = LN1(x) -> comb (fp32) + ylds (bf16).
// Tail: mlp1 (all 8 waves, ylds A-frags) -> mid frags back into ylds ->
// mlp2 (+b2 + y from comb) -> ln2 (red LDS cross-wave reduce) -> Hout/Hpk.
__global__ __launch_bounds__(512, 2) void attn_k(
    const ushort* Qp, const ushort* __restrict__ Kp,
    const ushort* __restrict__ Vp, const float* H,
    const float* __restrict__ g, const float* __restrict__ bt,
    const ushort* __restrict__ W1t, const float* __restrict__ b1p,
    const ushort* __restrict__ W2t, const float* __restrict__ b2p,
    const float* __restrict__ g2, const float* __restrict__ bt2,
    float* Hout, ushort* __restrict__ Hpk)
{
    int blk = blockIdx.x;            // pk*8 + b
    int pk = blk >> 3, b = blk & 7;
    int tid = threadIdx.x;
    int w = tid >> 6, l = tid & 63;
    int lr = l & 15, lg = l >> 4;
    int sel  = (w & 1) ^ ((w >> 2) & 1);
    int part = w >> 1;
    int s  = sel ? (127 - pk) : pk;  // 16-row slice index within batch
    int i0 = s * 16;
    int NT = (s >> 1) + 1;           // causal j-tiles of 32
    int j0 = (part * NT) >> 2;
    int j1 = ((part + 1) * NT) >> 2;

    __shared__ float comb[2][5440];      // 43.5 KB: combine, then y fp32
    __shared__ ushort ylds[2][4096];     // 16 KB: y frags, then mid frags
    __shared__ float red2[2][16][4][2];  // 1 KB: ln2 cross-wave stats

    const ushort* Qt    = Qp + ((size_t)(b*128 + s)) * 4096 + l*8;
    const ushort* Kbase = Kp + (size_t)(b*128) * 4096 + l*8;
    const ushort* Vbase = Vp + (size_t)(b*64) * 16 * 512 + l*8;

    short8 qb[8];
    #pragma unroll
    for (int kc = 0; kc < 8; ++kc) qb[kc] = *(const short8*)(Qt + kc*512);

    f32x4 oacc[16];
    #pragma unroll
    for (int et = 0; et < 16; ++et) oacc[et] = (f32x4){0.f,0.f,0.f,0.f};

    int ig = i0 + lr;
    for (int jt = j0; jt < j1; ++jt) {
        const ushort* Kt = Kbase + (size_t)(jt*2) * 4096;
        short8 ka0[8], ka1[8];
        #pragma unroll
        for (int kc = 0; kc < 8; ++kc) {
            ka0[kc] = *(const short8*)(Kt + kc*512);
            ka1[kc] = *(const short8*)(Kt + 4096 + kc*512);
        }
        const ushort* Vt = Vbase + (size_t)(jt*16) * 512;
        short8 vf[16];
        #pragma unroll
        for (int et = 0; et < 16; ++et)
            vf[et] = *(const short8*)(Vt + et*512);
        // QK^T (swapped), 4 independent chains
        f32x4 c0a = {0.f,0.f,0.f,0.f}, c0b = {0.f,0.f,0.f,0.f};
        f32x4 c1a = {0.f,0.f,0.f,0.f}, c1b = {0.f,0.f,0.f,0.f};
        #pragma unroll
        for (int kc = 0; kc < 8; kc += 2) {
            c0a = __builtin_amdgcn_mfma_f32_16x16x32_bf16(ka0[kc],   qb[kc],   c0a, 0,0,0);
            c0b = __builtin_amdgcn_mfma_f32_16x16x32_bf16(ka0[kc+1], qb[kc+1], c0b, 0,0,0);
            c1a = __builtin_amdgcn_mfma_f32_16x16x32_bf16(ka1[kc],   qb[kc],   c1a, 0,0,0);
            c1b = __builtin_amdgcn_mfma_f32_16x16x32_bf16(ka1[kc+1], qb[kc+1], c1b, 0,0,0);
        }
        f32x4 c0 = c0a + c0b, c1 = c1a + c1b;
        // relu + causal mask (j <= i)
        #pragma unroll
        for (int r = 0; r < 4; ++r) {
            int jg = jt*32 + lg*4 + r;
            c0[r] = (jg <= ig) ? fmaxf(c0[r], 0.f) : 0.f;
            c1[r] = (jg + 16 <= ig) ? fmaxf(c1[r], 0.f) : 0.f;
        }
        // pack to bf16 pairs and repack C-layout -> PV A-frag via shfl
        unsigned u0 = cvtpk(c0[0], c0[1]), u1 = cvtpk(c0[2], c0[3]);
        unsigned u2 = cvtpk(c1[0], c1[1]), u3 = cvtpk(c1[2], c1[3]);
        int srcA = 32*(lg & 1) + lr;
        int srcB = srcA + 16;
        unsigned a0A = __shfl((int)u0, srcA), a1A = __shfl((int)u1, srcA);
        unsigned a0B = __shfl((int)u0, srcB), a1B = __shfl((int)u1, srcB);
        unsigned b0A = __shfl((int)u2, srcA), b1A = __shfl((int)u3, srcA);
        unsigned b0B = __shfl((int)u2, srcB), b1B = __shfl((int)u3, srcB);
        bool lo = (lg < 2);
        union { unsigned u[4]; short8 v; } sv;
        sv.u[0] = lo ? a0A : b0A;
        sv.u[1] = lo ? a1A : b1A;
        sv.u[2] = lo ? a0B : b0B;
        sv.u[3] = lo ? a1B : b1B;
        short8 sa = sv.v;
        // PV: O[16][256] += S @ V_jt
        __builtin_amdgcn_s_setprio(1);
        #pragma unroll
        for (int et = 0; et < 16; ++et)
            oacc[et] = __builtin_amdgcn_mfma_f32_16x16x32_bf16(sa, vf[et], oacc[et], 0,0,0);
        __builtin_amdgcn_s_setprio(0);
    }

    // ---- 4-way combine (parts 1..3 -> LDS) ----
    float* cb = &comb[sel][0];
    #pragma unroll
    for (int rnd = 1; rnd <= 3; ++rnd) {
        if (part == rnd) {
            #pragma unroll
            for (int et = 0; et < 16; ++et)
                #pragma unroll
                for (int r = 0; r < 4; ++r) {
                    int idx = et*340 + l*5 + r;
                    float v = oacc[et][r];
                    if (rnd == 1) cb[idx] = v; else cb[idx] += v;
                }
        }
        __syncthreads();
    }
    // ---- epilogue by part 0: residual + scale + LN1 -> comb(y fp32) + ylds --
    if (part == 0) {
        float sm[4] = {0.f,0.f,0.f,0.f}, sq[4] = {0.f,0.f,0.f,0.f};
        #pragma unroll
        for (int et = 0; et < 16; ++et)
            #pragma unroll
            for (int r = 0; r < 4; ++r) {
                int irow = i0 + lg*4 + r;
                size_t base = ((size_t)(b*NN + irow))*EE + et*16 + lr;
                float x = H[base] + (oacc[et][r] + cb[et*340 + l*5 + r])
                                    * (1.0f / (float)(irow + 1));
                oacc[et][r] = x;
                sm[r] += x; sq[r] += x*x;
            }
        #pragma unroll
        for (int off = 1; off < 16; off <<= 1)
            #pragma unroll
            for (int r = 0; r < 4; ++r) {
                sm[r] += __shfl_xor(sm[r], off);
                sq[r] += __shfl_xor(sq[r], off);
            }
        float mean[4], inv[4];
        #pragma unroll
        for (int r = 0; r < 4; ++r) {
            mean[r] = sm[r] * (1.0f/256.0f);
            float var = sq[r] * (1.0f/256.0f) - mean[r]*mean[r];
            inv[r] = 1.0f / sqrtf(var + 1e-5f);
        }
        ushort* yl = &ylds[sel][0];
        #pragma unroll
        for (int et = 0; et < 16; ++et) {
            int col = et*16 + lr;
            float gv = g[col], bv = bt[col];
            #pragma unroll
            for (int r = 0; r < 4; ++r) {
                int row16 = lg*4 + r;
                float y = (oacc[et][r] - mean[r]) * inv[r] * gv + bv;
                cb[row16*256 + col] = y;   // y fp32 (comb region, now dead)
                int idx = (col >> 5)*512 + ((((col >> 3) & 3) << 4) + row16)*8
                        + (col & 7);
                yl[idx] = f2b(y);
            }
        }
    }
    __syncthreads();
    // ---- mlp1: all 8 waves; wave = (slice sel, 64-col group part) ----
    f32x4 macc[4];
    {
        const ushort* Ay = &ylds[sel][0] + l*8;
        const ushort* Bp = W1t + (size_t)(part*4)*4096 + l*8;
        #pragma unroll
        for (int cg = 0; cg < 4; ++cg) macc[cg] = (f32x4){0.f,0.f,0.f,0.f};
        #pragma unroll
        for (int kc = 0; kc < 8; ++kc) {
            short8 af = *(const short8*)(Ay + kc*512);
            #pragma unroll
            for (int cg = 0; cg < 4; ++cg) {
                short8 bf = *(const short8*)(Bp + (size_t)cg*4096 + kc*512);
                macc[cg] = __builtin_amdgcn_mfma_f32_16x16x32_bf16(af, bf, macc[cg], 0,0,0);
            }
        }
    }
    __syncthreads();   // all ylds (y-frag) reads complete
    // ---- write mid frags into ylds (overwrite) ----
    {
        ushort* yl = &ylds[sel][0];
        #pragma unroll
        for (int cg = 0; cg < 4; ++cg)
            #pragma unroll
            for (int r = 0; r < 4; ++r) {
                int col = part*64 + cg*16 + lr;
                int row16 = lg*4 + r;
                float x = fmaxf(macc[cg][r] + b1p[col], 0.f);
                int idx = (col >> 5)*512 + ((((col >> 3) & 3) << 4) + row16)*8
                        + (col & 7);
                yl[idx] = f2b(x);
            }
    }
    __syncthreads();
    // ---- mlp2 + b2 + y-residual, then ln2 ----
    float x2[4][4];
    {
        const ushort* Am = &ylds[sel][0] + l*8;
        const ushort* Bp = W2t + (size_t)(part*4)*4096 + l*8;
        f32x4 m2[4];
        #pragma unroll
        for (int cg = 0; cg < 4; ++cg) m2[cg] = (f32x4){0.f,0.f,0.f,0.f};
        #pragma unroll
        for (int kc = 0; kc < 8; ++kc) {
            short8 af = *(const short8*)(Am + kc*512);
            #pragma unroll
            for (int cg = 0; cg < 4; ++cg) {
                short8 bf = *(const short8*)(Bp + (size_t)cg*4096 + kc*512);
                m2[cg] = __builtin_amdgcn_mfma_f32_16x16x32_bf16(af, bf, m2[cg], 0,0,0);
            }
        }
        float sm2[4] = {0.f,0.f,0.f,0.f}, sq2[4] = {0.f,0.f,0.f,0.f};
        #pragma unroll
        for (int cg = 0; cg < 4; ++cg)
            #pragma unroll
            for (int r = 0; r < 4; ++r) {
                int col = part*64 + cg*16 + lr;
                int row16 = lg*4 + r;
                float v = m2[cg][r] + b2p[col] + cb[row16*256 + col];
                x2[cg][r] = v;
                sm2[r] += v; sq2[r] += v*v;
            }
        #pragma unroll
        for (int off = 1; off < 16; off <<= 1)
            #pragma unroll
            for (int r = 0; r < 4; ++r) {
                sm2[r] += __shfl_xor(sm2[r], off);
                sq2[r] += __shfl_xor(sq2[r], off);
            }
        if (lr == 0) {
            #pragma unroll
            for (int r = 0; r < 4; ++r) {
                red2[sel][lg*4 + r][part][0] = sm2[r];
                red2[sel][lg*4 + r][part][1] = sq2[r];
            }
        }
    }
    __syncthreads();
    {
        float mean[4], inv[4];
        #pragma unroll
        for (int r = 0; r < 4; ++r) {
            int row16 = lg*4 + r;
            float S  = red2[sel][row16][0][0] + red2[sel][row16][1][0]
                     + red2[sel][row16][2][0] + red2[sel][row16][3][0];
            float S2 = red2[sel][row16][0][1] + red2[sel][row16][1][1]
                     + red2[sel][row16][2][1] + red2[sel][row16][3][1];
            mean[r] = S * (1.0f/256.0f);
            float var = S2 * (1.0f/256.0f) - mean[r]*mean[r];
            inv[r] = 1.0f / sqrtf(var + 1e-5f);
        }
        #pragma unroll
        for (int cg = 0; cg < 4; ++cg) {
            int col = part*64 + cg*16 + lr;
            float gv = g2[col], bv = bt2[col];
            #pragma unroll
            for (int r = 0; r < 4; ++r) {
                int irow = i0 + lg*4 + r;
                size_t base = ((size_t)(b*NN + irow))*EE + col;
                float y2 = (x2[cg][r] - mean[r]) * inv[r] * gv + bv;
                Hout[base] = y2;
                Hpk[pk256(b*NN + irow, col)] = f2b(y2);
            }
        }
    }
}

// ---------------- prediction head (even rows only) ----------------
__global__ __launch_bounds__(256) void pred_k(
    const float* __restrict__ H, const float* __restrict__ Wp,
    const float* __restrict__ bp, float* __restrict__ out)
{
    int bt = blockIdx.x;
    int b = bt >> 10, t = bt & 1023;
    size_t row = (size_t)b*NN + 2*t;
    __shared__ float hs[256];
    __shared__ float pr[16][16];
    int tid = threadIdx.x;
    hs[tid] = H[row*EE + tid];
    __syncthreads();
    int c = tid & 15, seg = tid >> 4;
    float p = 0.f;
    if (c < 10) {
        #pragma unroll
        for (int e2 = 0; e2 < 16; ++e2)
            p = fmaf(hs[seg*16 + e2], Wp[(seg*16 + e2)*10 + c], p);
    }
    pr[seg][c] = p;
    __syncthreads();
    if (tid < 10) {
        float sacc = bp[tid];
        #pragma unroll
        for (int k2 = 0; k2 < 16; ++k2) sacc += pr[k2][tid];
        out[(size_t)bt*10 + tid] = sacc;
    }
}

extern "C" void kernel_launch(void* const* d_in, const int* in_sizes, int n_in,
                              void* d_out, int out_size, void* d_ws, size_t ws_size,
                              hipStream_t stream)
{
    const float* action_set = (const float*)d_in[1];
    const float* ctx_act    = (const float*)d_in[2];
    const float* ctx_rew    = (const float*)d_in[3];
    const float* W_embed    = (const float*)d_in[4];
    const float* b_embed    = (const float*)d_in[5];
    const float* wpe        = (const float*)d_in[6];
    const float* Wq         = (const float*)d_in[7];
    const float* Wk         = (const float*)d_in[8];
    const float* Wv         = (const float*)d_in[9];
    const float* ln1g       = (const float*)d_in[10];
    const float* ln1b       = (const float*)d_in[11];
    const float* W1         = (const float*)d_in[12];
    const float* b1         = (const float*)d_in[13];
    const float* W2         = (const float*)d_in[14];
    const float* b2         = (const float*)d_in[15];
    const float* ln2g       = (const float*)d_in[16];
    const float* ln2b       = (const float*)d_in[17];
    const float* Wp         = (const float*)d_in[18];
    const float* bp         = (const float*)d_in[19];
    float* out = (float*)d_out;

    float* ws = (float*)d_ws;
    const size_t SZ = (size_t)BB*NN*EE;   // 4,194,304
    size_t o = 0;
    float*  Hb   = ws;               o += SZ;        // fp32 residual stream (in/out)
    ushort* Hbf  = (ushort*)(ws+o);  o += SZ/2;      // packed bf16 stream
    ushort* Qp   = (ushort*)(ws+o);  o += SZ/2;      // packed Q
    ushort* Kpk  = (ushort*)(ws+o);  o += SZ/2;      // packed K
    ushort* Vpk  = (ushort*)(ws+o);  o += SZ/2;      // packed V
    ushort* WQKt = (ushort*)(ws+o);  o += 262144;
    ushort* WVt  = (ushort*)(ws+o);  o += 131072;
    ushort* W1t  = (ushort*)(ws+o);  o += 131072;
    ushort* W2t  = (ushort*)(ws+o);  o += 131072;
    float*  BE   = ws + o;

    wprep_k<<<320, 256, 0, stream>>>(Wq, Wk, Wv, W1, W2, WQKt, WVt, W1t, W2t);
    base_even_k<<<BB, 256, 0, stream>>>(action_set, W_embed, b_embed, BE);
    embed_k<<<BB*NN/8, 256, 0, stream>>>(BE, ctx_act, ctx_rew, W_embed, b_embed, wpe, Hb, Hbf);

    for (int l = 0; l < LL; ++l) {
        qkv_k<<<dim3(128, 6), 256, 0, stream>>>(
            Hbf, WQKt + (size_t)l*131072, WVt + (size_t)l*65536, Qp, Kpk, Vpk);
        // full layer tail: attn + ln1 + mlp1 + mlp2 + ln2 -> Hb, Hbf (in-place)
        attn_k<<<512, 512, 0, stream>>>(
            Qp, Kpk, Vpk, Hb, ln1g + l*EE, ln1b + l*EE,
            W1t + (size_t)l*65536, b1 + l*EE,
            W2t + (size_t)l*65536, b2 + l*EE,
            ln2g + l*EE, ln2b + l*EE, Hb, Hbf);
    }
    pred_k<<<BB*TT, 256, 0, stream>>>(Hb, Wp, bp, out);
}

// Round 14
// 368.731 us; speedup vs baseline: 1.9661x; 1.0836x over previous
//
#include <hip/hip_runtime.h>

// Transformer_67748814127473 — round 13: R12 + (a) y-region LDS stride 258
// (bank-conflict-free), (b) last layer computes even rows only (preds use
// rows 0::2; attention rows are independent). B=8, T=1024, N=2048, E=256, L=4.

#define BB 8
#define TT 1024
#define NN 2048
#define EE 256
#define LL 4
#define YST 258   // y fp32 LDS stride (4*258 % 32 == 8 -> worst 2-way, free)

typedef __attribute__((ext_vector_type(8))) short short8;
typedef __attribute__((ext_vector_type(4))) float f32x4;

__device__ inline ushort f2b(float f) {
    union { float f; unsigned u; } x; x.f = f;
    unsigned u = x.u;
    return (ushort)((u + 0x7fffu + ((u >> 16) & 1u)) >> 16);
}
__device__ inline unsigned cvtpk(float lo, float hi) {
    unsigned r;
    asm volatile("v_cvt_pk_bf16_f32 %0, %1, %2" : "=v"(r) : "v"(lo), "v"(hi));
    return r;
}
// fragment-linear pack for K=256 operands: tile16(row) x kchunk32 -> [lane][8]
__device__ inline size_t pk256(int row, int k) {
    return ((size_t)((row >> 4) * 8 + (k >> 5))) * 512
         + (size_t)((((k >> 3) & 3) * 16 + (row & 15)) * 8 + (k & 7));
}
// V pack: (batch, token n, embed e) -> B-frag linear
__device__ inline size_t vpk_idx(int bb, int nn, int e) {
    return ((size_t)(bb*64 + (nn >> 5)) * 16 + (e >> 4)) * 512
         + (size_t)((((nn >> 3) & 3) * 16 + (e & 15)) * 8 + (nn & 7));
}

// ---------------- weight prep: transpose + cast + frag-pack ----------------
__global__ __launch_bounds__(256) void wprep_k(
    const float* __restrict__ Wq, const float* __restrict__ Wk,
    const float* __restrict__ Wv, const float* __restrict__ W1,
    const float* __restrict__ W2,
    ushort* __restrict__ WQKt, ushort* __restrict__ WVt,
    ushort* __restrict__ W1t, ushort* __restrict__ W2t)
{
    int id = blockIdx.x;          // 320 = 20 matrices x 16 tiles
    int m = id >> 4, t = id & 15;
    int l = m / 5, which = m % 5;
    const float* src; ushort* dst;
    size_t o = (size_t)l * 65536;
    switch (which) {
        case 0: src = Wq + o; dst = WQKt + (size_t)l*131072;          break;
        case 1: src = Wk + o; dst = WQKt + (size_t)l*131072 + 65536;  break;
        case 2: src = Wv + o; dst = WVt + o; break;
        case 3: src = W1 + o; dst = W1t + o; break;
        default: src = W2 + o; dst = W2t + o; break;
    }
    int tk = (t >> 2) * 64;   // k block
    int tn = (t & 3) * 64;    // n block (output col)
    __shared__ ushort T[64][68];
    int tid = threadIdx.x;
    int r = tid >> 4, c4 = (tid & 15) * 4;
    #pragma unroll
    for (int it = 0; it < 4; ++it) {
        int k = r + it*16;
        float4 v = *(const float4*)&src[(size_t)(tk + k)*256 + tn + c4];
        T[k][c4+0] = f2b(v.x); T[k][c4+1] = f2b(v.y);
        T[k][c4+2] = f2b(v.z); T[k][c4+3] = f2b(v.w);
    }
    __syncthreads();
    #pragma unroll
    for (int it = 0; it < 4; ++it) {
        int n = tn + r + it*16;
        int k0 = tk + c4;
        ushort4 ov;
        ov.x = T[c4+0][n-tn]; ov.y = T[c4+1][n-tn];
        ov.z = T[c4+2][n-tn]; ov.w = T[c4+3][n-tn];
        *(ushort4*)&dst[pk256(n, k0)] = ov;
    }
}

// ---------------- per-batch even-row base vector ----------------
__global__ __launch_bounds__(256) void base_even_k(
    const float* __restrict__ aset, const float* __restrict__ We,
    const float* __restrict__ be, float* __restrict__ BE)
{
    int b = blockIdx.x; int e = threadIdx.x;
    __shared__ float as[640];
    for (int i = e; i < 640; i += 256) as[i] = aset[b*640 + i];
    __syncthreads();
    float s = We[651*EE + e] + be[e];
    for (int f = 0; f < 640; ++f) s = fmaf(as[f], We[f*EE + e], s);
    BE[b*EE + e] = s;
}

// ---------------- embedding (8 rows per block), fp32 + packed bf16 ----------
__global__ __launch_bounds__(256) void embed_k(
    const float* __restrict__ BE, const float* __restrict__ ca,
    const float* __restrict__ cr, const float* __restrict__ We,
    const float* __restrict__ be, const float* __restrict__ wpe,
    float* __restrict__ H, ushort* __restrict__ Hbf)
{
    int e = threadIdx.x;
    #pragma unroll
    for (int k = 0; k < 8; ++k) {
        int rb = blockIdx.x * 8 + k;
        int b = rb >> 11, n = rb & (NN-1);
        float h;
        if ((n & 1) == 0) {
            h = BE[b*EE + e];
        } else {
            int t = n >> 1;
            h = We[651*EE + e] + be[e];
            const float* cap = ca + (size_t)(b*TT + t)*10;
            #pragma unroll
            for (int i = 0; i < 10; ++i) h = fmaf(cap[i], We[(640+i)*EE + e], h);
            h = fmaf(cr[b*TT + t], We[650*EE + e], h);
        }
        h = fmaf((float)(n + 1), We[652*EE + e], h);
        h += wpe[(size_t)n*EE + e];
        H[(size_t)rb*EE + e] = h;
        Hbf[pk256(rb, e)] = f2b(h);
    }
}

// ---------------- merged QKV GEMM (packed in, packed out) -------------------
__global__ __launch_bounds__(256, 2) void qkv_k(
    const ushort* __restrict__ A, const ushort* __restrict__ WQK,
    const ushort* __restrict__ WV,
    ushort* __restrict__ Qo, ushort* __restrict__ Ko, ushort* __restrict__ Vo)
{
    int tid = threadIdx.x;
    int w = tid >> 6, l = tid & 63;
    int lr = l & 15, lg = l >> 4;
    int wr = w >> 1, wc = w & 1;
    int rt0 = blockIdx.x * 8 + wr*4;
    int ct0 = blockIdx.y * 8 + wc*4;
    const ushort* Ap = A + (size_t)rt0*4096 + l*8;
    const ushort* Bp = (blockIdx.y < 4 ? WQK + (size_t)ct0*4096
                                       : WV + (size_t)(ct0-32)*4096) + l*8;
    f32x4 acc[4][4];
    #pragma unroll
    for (int i = 0; i < 4; ++i)
        #pragma unroll
        for (int j = 0; j < 4; ++j) acc[i][j] = (f32x4){0.f,0.f,0.f,0.f};
    #pragma unroll
    for (int kc = 0; kc < 8; ++kc) {
        short8 af[4], bf[4];
        #pragma unroll
        for (int rg = 0; rg < 4; ++rg) af[rg] = *(const short8*)(Ap + (size_t)rg*4096 + kc*512);
        #pragma unroll
        for (int cg = 0; cg < 4; ++cg) bf[cg] = *(const short8*)(Bp + (size_t)cg*4096 + kc*512);
        #pragma unroll
        for (int rg = 0; rg < 4; ++rg)
            #pragma unroll
            for (int cg = 0; cg < 4; ++cg)
                acc[rg][cg] = __builtin_amdgcn_mfma_f32_16x16x32_bf16(af[rg], bf[cg], acc[rg][cg], 0,0,0);
    }
    #pragma unroll
    for (int rg = 0; rg < 4; ++rg)
        #pragma unroll
        for (int cg = 0; cg < 4; ++cg)
            #pragma unroll
            for (int r = 0; r < 4; ++r) {
                int row = rt0*16 + rg*16 + lg*4 + r;
                int col = ct0*16 + cg*16 + lr;
                ushort xv = f2b(acc[rg][cg][r]);
                if (col < 256)      Qo[pk256(row, col)] = xv;
                else if (col < 512) Ko[pk256(row, col - 256)] = xv;
                else {
                    int e = col - 512, bb = row >> 11, nn = row & (NN-1);
                    Vo[vpk_idx(bb, nn, e)] = xv;
                }
            }
}

// ---------------- attention + ln1 + mlp1 + mlp2 + ln2 (full layer tail) -----
// EVEN=0: 512 blocks, slices of 16 consecutive rows (s=0..127 per batch).
// EVEN=1 (last layer): 256 blocks, wave covers the 16 EVEN rows of a 32-row
// window (s=0..63); odd rows are dead (preds read rows 0::2 only).
template<int EVEN>
__global__ __launch_bounds__(512, 2) void attn_k(
    const ushort* Qp, const ushort* __restrict__ Kp,
    const ushort* __restrict__ Vp, const float* H,
    const float* __restrict__ g, const float* __restrict__ bt,
    const ushort* __restrict__ W1t, const float* __restrict__ b1p,
    const ushort* __restrict__ W2t, const float* __restrict__ b2p,
    const float* __restrict__ g2, const float* __restrict__ bt2,
    float* Hout, ushort* __restrict__ Hpk)
{
    const int SMAX = EVEN ? 63 : 127;
    const int RS   = EVEN ? 2 : 1;
    int blk = blockIdx.x;            // pk*8 + b
    int pk = blk >> 3, b = blk & 7;
    int tid = threadIdx.x;
    int w = tid >> 6, l = tid & 63;
    int lr = l & 15, lg = l >> 4;
    int sel  = (w & 1) ^ ((w >> 2) & 1);
    int part = w >> 1;
    int s  = sel ? (SMAX - pk) : pk;         // slice index within batch
    int i0 = EVEN ? s*32 : s*16;             // base physical row
    int NT = EVEN ? (s + 1) : ((s >> 1) + 1); // causal j-tiles of 32
    int j0 = (part * NT) >> 2;
    int j1 = ((part + 1) * NT) >> 2;

    __shared__ float comb[2][5440];      // 43.5 KB: combine, then y fp32
    __shared__ ushort ylds[2][4096];     // 16 KB: y frags, then mid frags
    __shared__ float red2[2][16][4][2];  // 1 KB: ln2 cross-wave stats

    const ushort* Kbase = Kp + (size_t)(b*128) * 4096 + l*8;
    const ushort* Vbase = Vp + (size_t)(b*64) * 16 * 512 + l*8;

    // Q rows: lane lr -> physical row i0 + RS*lr (gathered when EVEN)
    short8 qb[8];
    {
        const ushort* Qb0 = Qp + (size_t)(b*128) * 4096;
        int qrow = i0 + RS*lr;
        #pragma unroll
        for (int kc = 0; kc < 8; ++kc)
            qb[kc] = *(const short8*)&Qb0[pk256(qrow, kc*32 + lg*8)];
    }

    f32x4 oacc[16];
    #pragma unroll
    for (int et = 0; et < 16; ++et) oacc[et] = (f32x4){0.f,0.f,0.f,0.f};

    int ig = i0 + RS*lr;
    for (int jt = j0; jt < j1; ++jt) {
        const ushort* Kt = Kbase + (size_t)(jt*2) * 4096;
        short8 ka0[8], ka1[8];
        #pragma unroll
        for (int kc = 0; kc < 8; ++kc) {
            ka0[kc] = *(const short8*)(Kt + kc*512);
            ka1[kc] = *(const short8*)(Kt + 4096 + kc*512);
        }
        const ushort* Vt = Vbase + (size_t)(jt*16) * 512;
        short8 vf[16];
        #pragma unroll
        for (int et = 0; et < 16; ++et)
            vf[et] = *(const short8*)(Vt + et*512);
        // QK^T (swapped), 4 independent chains
        f32x4 c0a = {0.f,0.f,0.f,0.f}, c0b = {0.f,0.f,0.f,0.f};
        f32x4 c1a = {0.f,0.f,0.f,0.f}, c1b = {0.f,0.f,0.f,0.f};
        #pragma unroll
        for (int kc = 0; kc < 8; kc += 2) {
            c0a = __builtin_amdgcn_mfma_f32_16x16x32_bf16(ka0[kc],   qb[kc],   c0a, 0,0,0);
            c0b = __builtin_amdgcn_mfma_f32_16x16x32_bf16(ka0[kc+1], qb[kc+1], c0b, 0,0,0);
            c1a = __builtin_amdgcn_mfma_f32_16x16x32_bf16(ka1[kc],   qb[kc],   c1a, 0,0,0);
            c1b = __builtin_amdgcn_mfma_f32_16x16x32_bf16(ka1[kc+1], qb[kc+1], c1b, 0,0,0);
        }
        f32x4 c0 = c0a + c0b, c1 = c1a + c1b;
        // relu + causal mask (j <= i)
        #pragma unroll
        for (int r = 0; r < 4; ++r) {
            int jg = jt*32 + lg*4 + r;
            c0[r] = (jg <= ig) ? fmaxf(c0[r], 0.f) : 0.f;
            c1[r] = (jg + 16 <= ig) ? fmaxf(c1[r], 0.f) : 0.f;
        }
        // pack to bf16 pairs and repack C-layout -> PV A-frag via shfl
        unsigned u0 = cvtpk(c0[0], c0[1]), u1 = cvtpk(c0[2], c0[3]);
        unsigned u2 = cvtpk(c1[0], c1[1]), u3 = cvtpk(c1[2], c1[3]);
        int srcA = 32*(lg & 1) + lr;
        int srcB = srcA + 16;
        unsigned a0A = __shfl((int)u0, srcA), a1A = __shfl((int)u1, srcA);
        unsigned a0B = __shfl((int)u0, srcB), a1B = __shfl((int)u1, srcB);
        unsigned b0A = __shfl((int)u2, srcA), b1A = __shfl((int)u3, srcA);
        unsigned b0B = __shfl((int)u2, srcB), b1B = __shfl((int)u3, srcB);
        bool lo = (lg < 2);
        union { unsigned u[4]; short8 v; } sv;
        sv.u[0] = lo ? a0A : b0A;
        sv.u[1] = lo ? a1A : b1A;
        sv.u[2] = lo ? a0B : b0B;
        sv.u[3] = lo ? a1B : b1B;
        short8 sa = sv.v;
        // PV: O[16][256] += S @ V_jt
        __builtin_amdgcn_s_setprio(1);
        #pragma unroll
        for (int et = 0; et < 16; ++et)
            oacc[et] = __builtin_amdgcn_mfma_f32_16x16x32_bf16(sa, vf[et], oacc[et], 0,0,0);
        __builtin_amdgcn_s_setprio(0);
    }

    // ---- 4-way combine (parts 1..3 -> LDS) ----
    float* cb = &comb[sel][0];
    #pragma unroll
    for (int rnd = 1; rnd <= 3; ++rnd) {
        if (part == rnd) {
            #pragma unroll
            for (int et = 0; et < 16; ++et)
                #pragma unroll
                for (int r = 0; r < 4; ++r) {
                    int idx = et*340 + l*5 + r;
                    float v = oacc[et][r];
                    if (rnd == 1) cb[idx] = v; else cb[idx] += v;
                }
        }
        __syncthreads();
    }
    // ---- epilogue by part 0: residual + scale + LN1 -> comb(y fp32) + ylds --
    if (part == 0) {
        float sm[4] = {0.f,0.f,0.f,0.f}, sq[4] = {0.f,0.f,0.f,0.f};
        #pragma unroll
        for (int et = 0; et < 16; ++et)
            #pragma unroll
            for (int r = 0; r < 4; ++r) {
                int irow = i0 + RS*(lg*4 + r);
                size_t base = ((size_t)(b*NN + irow))*EE + et*16 + lr;
                float x = H[base] + (oacc[et][r] + cb[et*340 + l*5 + r])
                                    * (1.0f / (float)(irow + 1));
                oacc[et][r] = x;
                sm[r] += x; sq[r] += x*x;
            }
        #pragma unroll
        for (int off = 1; off < 16; off <<= 1)
            #pragma unroll
            for (int r = 0; r < 4; ++r) {
                sm[r] += __shfl_xor(sm[r], off);
                sq[r] += __shfl_xor(sq[r], off);
            }
        float mean[4], inv[4];
        #pragma unroll
        for (int r = 0; r < 4; ++r) {
            mean[r] = sm[r] * (1.0f/256.0f);
            float var = sq[r] * (1.0f/256.0f) - mean[r]*mean[r];
            inv[r] = 1.0f / sqrtf(var + 1e-5f);
        }
        ushort* yl = &ylds[sel][0];
        #pragma unroll
        for (int et = 0; et < 16; ++et) {
            int col = et*16 + lr;
            float gv = g[col], bv = bt[col];
            #pragma unroll
            for (int r = 0; r < 4; ++r) {
                int row16 = lg*4 + r;
                float y = (oacc[et][r] - mean[r]) * inv[r] * gv + bv;
                cb[row16*YST + col] = y;   // y fp32 (comb region, now dead)
                int idx = (col >> 5)*512 + ((((col >> 3) & 3) << 4) + row16)*8
                        + (col & 7);
                yl[idx] = f2b(y);
            }
        }
    }
    __syncthreads();
    // ---- mlp1: all 8 waves; wave = (slice sel, 64-col group part) ----
    f32x4 macc[4];
    {
        const ushort* Ay = &ylds[sel][0] + l*8;
        const ushort* Bp = W1t + (size_t)(part*4)*4096 + l*8;
        #pragma unroll
        for (int cg = 0; cg < 4; ++cg) macc[cg] = (f32x4){0.f,0.f,0.f,0.f};
        #pragma unroll
        for (int kc = 0; kc < 8; ++kc) {
            short8 af = *(const short8*)(Ay + kc*512);
            #pragma unroll
            for (int cg = 0; cg < 4; ++cg) {
                short8 bf = *(const short8*)(Bp + (size_t)cg*4096 + kc*512);
                macc[cg] = __builtin_amdgcn_mfma_f32_16x16x32_bf16(af, bf, macc[cg], 0,0,0);
            }
        }
    }
    __syncthreads();   // all ylds (y-frag) reads complete
    // ---- write mid frags into ylds (overwrite) ----
    {
        ushort* yl = &ylds[sel][0];
        #pragma unroll
        for (int cg = 0; cg < 4; ++cg)
            #pragma unroll
            for (int r = 0; r < 4; ++r) {
                int col = part*64 + cg*16 + lr;
                int row16 = lg*4 + r;
                float x = fmaxf(macc[cg][r] + b1p[col], 0.f);
                int idx = (col >> 5)*512 + ((((col >> 3) & 3) << 4) + row16)*8
                        + (col & 7);
                yl[idx] = f2b(x);
            }
    }
    __syncthreads();
    // ---- mlp2 + b2 + y-residual, then ln2 ----
    float x2[4][4];
    {
        const ushort* Am = &ylds[sel][0] + l*8;
        const ushort* Bp = W2t + (size_t)(part*4)*4096 + l*8;
        f32x4 m2[4];
        #pragma unroll
        for (int cg = 0; cg < 4; ++cg) m2[cg] = (f32x4){0.f,0.f,0.f,0.f};
        #pragma unroll
        for (int kc = 0; kc < 8; ++kc) {
            short8 af = *(const short8*)(Am + kc*512);
            #pragma unroll
            for (int cg = 0; cg < 4; ++cg) {
                short8 bf = *(const short8*)(Bp + (size_t)cg*4096 + kc*512);
                m2[cg] = __builtin_amdgcn_mfma_f32_16x16x32_bf16(af, bf, m2[cg], 0,0,0);
            }
        }
        float sm2[4] = {0.f,0.f,0.f,0.f}, sq2[4] = {0.f,0.f,0.f,0.f};
        #pragma unroll
        for (int cg = 0; cg < 4; ++cg)
            #pragma unroll
            for (int r = 0; r < 4; ++r) {
                int col = part*64 + cg*16 + lr;
                int row16 = lg*4 + r;
                float v = m2[cg][r] + b2p[col] + cb[row16*YST + col];
                x2[cg][r] = v;
                sm2[r] += v; sq2[r] += v*v;
            }
        #pragma unroll
        for (int off = 1; off < 16; off <<= 1)
            #pragma unroll
            for (int r = 0; r < 4; ++r) {
                sm2[r] += __shfl_xor(sm2[r], off);
                sq2[r] += __shfl_xor(sq2[r], off);
            }
        if (lr == 0) {
            #pragma unroll
            for (int r = 0; r < 4; ++r) {
                red2[sel][lg*4 + r][part][0] = sm2[r];
                red2[sel][lg*4 + r][part][1] = sq2[r];
            }
        }
    }
    __syncthreads();
    {
        float mean[4], inv[4];
        #pragma unroll
        for (int r = 0; r < 4; ++r) {
            int row16 = lg*4 + r;
            float S  = red2[sel][row16][0][0] + red2[sel][row16][1][0]
                     + red2[sel][row16][2][0] + red2[sel][row16][3][0];
            float S2 = red2[sel][row16][0][1] + red2[sel][row16][1][1]
                     + red2[sel][row16][2][1] + red2[sel][row16][3][1];
            mean[r] = S * (1.0f/256.0f);
            float var = S2 * (1.0f/256.0f) - mean[r]*mean[r];
            inv[r] = 1.0f / sqrtf(var + 1e-5f);
        }
        #pragma unroll
        for (int cg = 0; cg < 4; ++cg) {
            int col = part*64 + cg*16 + lr;
            float gv = g2[col], bv = bt2[col];
            #pragma unroll
            for (int r = 0; r < 4; ++r) {
                int irow = i0 + RS*(lg*4 + r);
                size_t base = ((size_t)(b*NN + irow))*EE + col;
                float y2 = (x2[cg][r] - mean[r]) * inv[r] * gv + bv;
                Hout[base] = y2;
                Hpk[pk256(b*NN + irow, col)] = f2b(y2);
            }
        }
    }
}

// ---------------- prediction head (even rows only) ----------------
__global__ __launch_bounds__(256) void pred_k(
    const float* __restrict__ H, const float* __restrict__ Wp,
    const float* __restrict__ bp, float* __restrict__ out)
{
    int bt = blockIdx.x;
    int b = bt >> 10, t = bt & 1023;
    size_t row = (size_t)b*NN + 2*t;
    __shared__ float hs[256];
    __shared__ float pr[16][16];
    int tid = threadIdx.x;
    hs[tid] = H[row*EE + tid];
    __syncthreads();
    int c = tid & 15, seg = tid >> 4;
    float p = 0.f;
    if (c < 10) {
        #pragma unroll
        for (int e2 = 0; e2 < 16; ++e2)
            p = fmaf(hs[seg*16 + e2], Wp[(seg*16 + e2)*10 + c], p);
    }
    pr[seg][c] = p;
    __syncthreads();
    if (tid < 10) {
        float sacc = bp[tid];
        #pragma unroll
        for (int k2 = 0; k2 < 16; ++k2) sacc += pr[k2][tid];
        out[(size_t)bt*10 + tid] = sacc;
    }
}

extern "C" void kernel_launch(void* const* d_in, const int* in_sizes, int n_in,
                              void* d_out, int out_size, void* d_ws, size_t ws_size,
                              hipStream_t stream)
{
    const float* action_set = (const float*)d_in[1];
    const float* ctx_act    = (const float*)d_in[2];
    const float* ctx_rew    = (const float*)d_in[3];
    const float* W_embed    = (const float*)d_in[4];
    const float* b_embed    = (const float*)d_in[5];
    const float* wpe        = (const float*)d_in[6];
    const float* Wq         = (const float*)d_in[7];
    const float* Wk         = (const float*)d_in[8];
    const float* Wv         = (const float*)d_in[9];
    const float* ln1g       = (const float*)d_in[10];
    const float* ln1b       = (const float*)d_in[11];
    const float* W1         = (const float*)d_in[12];
    const float* b1         = (const float*)d_in[13];
    const float* W2         = (const float*)d_in[14];
    const float* b2         = (const float*)d_in[15];
    const float* ln2g       = (const float*)d_in[16];
    const float* ln2b       = (const float*)d_in[17];
    const float* Wp         = (const float*)d_in[18];
    const float* bp         = (const float*)d_in[19];
    float* out = (float*)d_out;

    float* ws = (float*)d_ws;
    const size_t SZ = (size_t)BB*NN*EE;   // 4,194,304
    size_t o = 0;
    float*  Hb   = ws;               o += SZ;        // fp32 residual stream (in/out)
    ushort* Hbf  = (ushort*)(ws+o);  o += SZ/2;      // packed bf16 stream
    ushort* Qp   = (ushort*)(ws+o);  o += SZ/2;      // packed Q
    ushort* Kpk  = (ushort*)(ws+o);  o += SZ/2;      // packed K
    ushort* Vpk  = (ushort*)(ws+o);  o += SZ/2;      // packed V
    ushort* WQKt = (ushort*)(ws+o);  o += 262144;
    ushort* WVt  = (ushort*)(ws+o);  o += 131072;
    ushort* W1t  = (ushort*)(ws+o);  o += 131072;
    ushort* W2t  = (ushort*)(ws+o);  o += 131072;
    float*  BE   = ws + o;

    wprep_k<<<320, 256, 0, stream>>>(Wq, Wk, Wv, W1, W2, WQKt, WVt, W1t, W2t);
    base_even_k<<<BB, 256, 0, stream>>>(action_set, W_embed, b_embed, BE);
    embed_k<<<BB*NN/8, 256, 0, stream>>>(BE, ctx_act, ctx_rew, W_embed, b_embed, wpe, Hb, Hbf);

    for (int l = 0; l < LL; ++l) {
        qkv_k<<<dim3(128, 6), 256, 0, stream>>>(
            Hbf, WQKt + (size_t)l*131072, WVt + (size_t)l*65536, Qp, Kpk, Vpk);
        // full layer tail: attn + ln1 + mlp1 + mlp2 + ln2 -> Hb, Hbf (in-place)
        if (l < LL-1) {
            attn_k<0><<<512, 512, 0, stream>>>(
                Qp, Kpk, Vpk, Hb, ln1g + l*EE, ln1b + l*EE,
                W1t + (size_t)l*65536, b1 + l*EE,
                W2t + (size_t)l*65536, b2 + l*EE,
                ln2g + l*EE, ln2b + l*EE, Hb, Hbf);
        } else {
            // last layer: only even rows are observable (preds = rows 0::2)
            attn_k<1><<<256, 512, 0, stream>>>(
                Qp, Kpk, Vpk, Hb, ln1g + l*EE, ln1b + l*EE,
                W1t + (size_t)l*65536, b1 + l*EE,
                W2t + (size_t)l*65536, b2 + l*EE,
                ln2g + l*EE, ln2b + l*EE, Hb, Hbf);
        }
    }
    pred_k<<<BB*TT, 256, 0, stream>>>(Hb, Wp, bp, out);
}